// Round 4
// baseline (1934.912 us; speedup 1.0000x reference)
//
#include <hip/hip_runtime.h>
#include <hip/hip_bf16.h>

#define NND 50000
#define NE  1600000
#define TT  8
#define NBS ((NND + 255) / 256)   // 196 blocks over nodes

// ---------------- preprocessing ----------------

__global__ void k_init(int* __restrict__ deg, float* __restrict__ ppool) {
  int i = blockIdx.x * 256 + threadIdx.x;
  if (i < NND) deg[i] = 1;              // self-loop
  if (i < TT * 64) ppool[i] = 0.f;
}

__global__ void k_deg(const int* __restrict__ ei, int* __restrict__ deg) {
  int e = blockIdx.x * 256 + threadIdx.x;
  if (e < NE) atomicAdd(&deg[ei[NE + e]], 1);
}

__global__ void k_dinv(const int* __restrict__ deg, float* __restrict__ dinv) {
  int n = blockIdx.x * 256 + threadIdx.x;
  if (n < NND) dinv[n] = rsqrtf((float)deg[n]);
}

__global__ void k_scan1(const int* __restrict__ deg, int* __restrict__ bsum) {
  __shared__ int sh[256];
  int n = blockIdx.x * 256 + threadIdx.x;
  sh[threadIdx.x] = (n < NND) ? deg[n] : 0;
  __syncthreads();
  for (int o = 128; o > 0; o >>= 1) {
    if (threadIdx.x < o) sh[threadIdx.x] += sh[threadIdx.x + o];
    __syncthreads();
  }
  if (threadIdx.x == 0) bsum[blockIdx.x] = sh[0];
}

__global__ void k_scan2(const int* __restrict__ bsum, int* __restrict__ boff) {
  __shared__ int sh[256];
  int tid = threadIdx.x;
  int v = (tid < NBS) ? bsum[tid] : 0;
  sh[tid] = v;
  __syncthreads();
  for (int o = 1; o < 256; o <<= 1) {
    int t = (tid >= o) ? sh[tid - o] : 0;
    __syncthreads();
    sh[tid] += t;
    __syncthreads();
  }
  boff[tid] = sh[tid] - v;  // exclusive
}

__global__ void k_scan3(const int* __restrict__ deg, const int* __restrict__ boff,
                        int* __restrict__ offs, int* __restrict__ cursor,
                        int* __restrict__ csr) {
  __shared__ int sh[256];
  int tid = threadIdx.x;
  int n = blockIdx.x * 256 + tid;
  int v = (n < NND) ? deg[n] : 0;
  sh[tid] = v;
  __syncthreads();
  for (int o = 1; o < 256; o <<= 1) {
    int t2 = (tid >= o) ? sh[tid - o] : 0;
    __syncthreads();
    sh[tid] += t2;
    __syncthreads();
  }
  if (n < NND) {
    int x = boff[blockIdx.x] + sh[tid] - v;  // exclusive global offset
    offs[n] = x;
    cursor[n] = x + 1;   // slot 0 of each node = self-loop
    csr[x] = n;
  }
}

// dst-range-limited scatter pass: csr write window per pass ~1.65MB (fits L2),
// so dirty lines absorb all their writes before eviction. Old single-pass
// version: 100 MB of 64B-line writebacks for 6.4 MB of payload (137 us).
__global__ void k_scatter(const int* __restrict__ ei, int* __restrict__ cursor,
                          int* __restrict__ csr, int lo, int hi) {
  int e = blockIdx.x * 256 + threadIdx.x;
  if (e < NE) {
    int d = ei[NE + e];
    if (d >= lo && d < hi) {
      int p = atomicAdd(&cursor[d], 1);
      csr[p] = ei[e];
    }
  }
}

// x_seq [T][N][3] -> xs4 [N][T][4] (padded, pre-scaled by dinv[n])
__global__ void k_xs(const float* __restrict__ x, const float* __restrict__ dinv,
                     float* __restrict__ xs4) {
  int g = blockIdx.x * 256 + threadIdx.x;
  if (g >= NND * TT * 4) return;
  int n = g >> 5, r = g & 31, t = r >> 2, c = r & 3;
  float v = 0.f;
  if (c < 3) v = x[(t * NND + n) * 3 + c] * dinv[n];
  xs4[g] = v;
}

// ---------------- layer 1 ----------------

// y[t][n][0..2] = dinv[n] * sum_{s in nbr(n)} xs[s][t][0..2]   (8 threads per node)
__global__ void k_yagg(const int* __restrict__ offs, const int* __restrict__ deg,
                       const int* __restrict__ csr, const float4* __restrict__ xs4,
                       const float* __restrict__ dinv, float* __restrict__ y) {
  int g = blockIdx.x * 256 + threadIdx.x;
  int n = g >> 3, t = g & 7;
  if (n >= NND) return;
  int o0 = offs[n], d = deg[n];
  float a0 = 0.f, a1 = 0.f, a2 = 0.f;
  int i = 0;
  for (; i + 2 <= d; i += 2) {
    int s0 = csr[o0 + i], s1 = csr[o0 + i + 1];
    float4 v0 = xs4[s0 * 8 + t];
    float4 v1 = xs4[s1 * 8 + t];
    a0 += v0.x + v1.x; a1 += v0.y + v1.y; a2 += v0.z + v1.z;
  }
  if (i < d) {
    float4 v = xs4[csr[o0 + i] * 8 + t];
    a0 += v.x; a1 += v.y; a2 += v.z;
  }
  float dn = dinv[n];
  size_t b = ((size_t)t * NND + n) * 3;
  y[b] = a0 * dn; y[b + 1] = a1 * dn; y[b + 2] = a2 * dn;
}

// h1s[n][c] = bf16( dinv[n] * relu(y[t][n]·W1[:,c] + b1[c]) )
__global__ void k_h1(const float* __restrict__ y, const float* __restrict__ W1,
                     const float* __restrict__ b1, const float* __restrict__ dinv,
                     __hip_bfloat16* __restrict__ h1s, int t) {
  int g = blockIdx.x * 256 + threadIdx.x;
  int n = g >> 6, c = g & 63;
  if (n >= NND) return;
  const float* yy = y + ((size_t)t * NND + n) * 3;
  float y0 = yy[0], y1 = yy[1], y2 = yy[2];
  float v = fmaf(y2, W1[128 + c], fmaf(y1, W1[64 + c], fmaf(y0, W1[c], b1[c])));
  h1s[g] = __float2bfloat16(fmaxf(v, 0.f) * dinv[n]);
}

// ---------------- layer 2: fused aggregate + GEMM + pool ----------------

// Per block: 128 dst rows. Phase 1: each wave gathers 32 rows' neighbor sums
// (lane = channel, bf16 loads, 128B/neighbor) straight into swizzled LDS As.
// Phase 2: As[128,64] @ W2[64,64], relu+bias, row-sum into ppool[t].
// Eliminates the agg2 global round-trip (205 MB across the 8 t).
__launch_bounds__(256)
__global__ void k_aggemm(const int* __restrict__ offs, const int* __restrict__ deg,
                         const int* __restrict__ csr,
                         const __hip_bfloat16* __restrict__ h1s,
                         const float* __restrict__ dinv,
                         const float* __restrict__ W2, const float* __restrict__ b2,
                         float* __restrict__ ppool, int t) {
  __shared__ float As[128 * 64];   // 32 KB, chunk-swizzled
  __shared__ float Ws[64 * 64];    // 16 KB, W2^T, chunk-swizzled
  __shared__ float pool[64];
  int tid = threadIdx.x;
  int rows0 = blockIdx.x * 128;
  if (tid < 64) pool[tid] = 0.f;
  // Ws[j][swz(k)] = W2[k][j]
  for (int i = 0; i < 16; ++i) {
    int idx = i * 256 + tid;
    int k = idx >> 6, j = idx & 63;
    Ws[j * 64 + (((k >> 2) ^ ((j >> 3) & 7)) << 2) + (k & 3)] = W2[idx];
  }

  int wv = tid >> 6, lane = tid & 63;
  for (int rr = 0; rr < 32; ++rr) {
    int row = wv * 32 + rr;
    int n = rows0 + row;
    float acc0 = 0.f, acc1 = 0.f;
    if (n < NND) {
      int o0 = offs[n], d = deg[n];
      int i = 0;
      for (; i + 4 <= d; i += 4) {
        int s0 = csr[o0 + i], s1 = csr[o0 + i + 1];
        int s2 = csr[o0 + i + 2], s3 = csr[o0 + i + 3];
        acc0 += __bfloat162float(h1s[(size_t)s0 * 64 + lane]);
        acc1 += __bfloat162float(h1s[(size_t)s1 * 64 + lane]);
        acc0 += __bfloat162float(h1s[(size_t)s2 * 64 + lane]);
        acc1 += __bfloat162float(h1s[(size_t)s3 * 64 + lane]);
      }
      for (; i < d; ++i) acc0 += __bfloat162float(h1s[(size_t)csr[o0 + i] * 64 + lane]);
      acc0 = (acc0 + acc1) * dinv[n];
    }
    // element (row, k=lane) at row*64 + ((k>>2 ^ (row>>3)&7)<<2) + (k&3)
    As[row * 64 + ((((lane >> 2) ^ ((row >> 3) & 7)) << 2) | (lane & 3))] = acc0;
  }
  __syncthreads();

  int rowg = tid >> 3, colg = tid & 7;
  int r0 = rowg * 4, c0 = colg * 8;
  float acc[4][8];
  for (int a = 0; a < 4; ++a)
    for (int b = 0; b < 8; ++b) acc[a][b] = 0.f;
  for (int k4 = 0; k4 < 16; ++k4) {
    float4 w[8];
    for (int cc = 0; cc < 8; ++cc)
      w[cc] = *(const float4*)&Ws[(c0 + cc) * 64 + ((k4 ^ colg) << 2)];
    for (int rr = 0; rr < 4; ++rr) {
      int r = r0 + rr;
      float4 av = *(const float4*)&As[r * 64 + ((k4 ^ ((r >> 3) & 7)) << 2)];
      for (int cc = 0; cc < 8; ++cc) {
        acc[rr][cc] += av.x * w[cc].x;
        acc[rr][cc] += av.y * w[cc].y;
        acc[rr][cc] += av.z * w[cc].z;
        acc[rr][cc] += av.w * w[cc].w;
      }
    }
  }

  float b2c[8];
  for (int cc = 0; cc < 8; ++cc) b2c[cc] = b2[c0 + cc];
  float csum[8];
  for (int cc = 0; cc < 8; ++cc) csum[cc] = 0.f;
  for (int rr = 0; rr < 4; ++rr) {
    if (rows0 + r0 + rr < NND) {
      for (int cc = 0; cc < 8; ++cc)
        csum[cc] += fmaxf(acc[rr][cc] + b2c[cc], 0.f);
    }
  }
  for (int cc = 0; cc < 8; ++cc) atomicAdd(&pool[c0 + cc], csum[cc]);
  __syncthreads();
  if (tid < 64) atomicAdd(&ppool[t * 64 + tid], pool[tid]);
}

// ---------------- GRU + fc ----------------

__global__ void k_twih(const float* __restrict__ w, float* __restrict__ wt) {
  int g = blockIdx.x * 256 + threadIdx.x;
  if (g < 384 * 64) { int r = g >> 6, k = g & 63; wt[k * 384 + r] = w[g]; }
}
__global__ void k_twhh(const float* __restrict__ w, float* __restrict__ wt) {
  int g = blockIdx.x * 256 + threadIdx.x;
  if (g < 384 * 128) { int r = g >> 7, k = g & 127; wt[k * 384 + r] = w[g]; }
}

// One block, 384 threads: thread j owns gate-output j; weight columns in
// registers, loaded once (fixed the 330 us L2-latency version).
__launch_bounds__(384, 2)
__global__ void k_gru(const float* __restrict__ ppool, const float* __restrict__ wihT,
                      const float* __restrict__ whhT, const float* __restrict__ b_ih,
                      const float* __restrict__ b_hh, const float* __restrict__ fc_w,
                      const float* __restrict__ fc_b, float* __restrict__ out) {
  __shared__ float x[64], h[128], gi_s[384], gh_s[384], red[128];
  int j = threadIdx.x;  // 0..383
  float wih[64];
#pragma unroll
  for (int k = 0; k < 64; ++k) wih[k] = wihT[k * 384 + j];
  float whh[128];
#pragma unroll
  for (int k = 0; k < 128; ++k) whh[k] = whhT[k * 384 + j];
  float bi = b_ih[j], bh = b_hh[j];
  if (j < 128) h[j] = 0.f;
  const float invn = 1.0f / (float)NND;
  for (int t = 0; t < TT; ++t) {
    if (j < 64) x[j] = ppool[t * 64 + j] * invn;
    __syncthreads();
    float gi = bi, gh = bh;
#pragma unroll
    for (int k4 = 0; k4 < 16; ++k4) {
      float4 xv = *(const float4*)&x[k4 * 4];
      gi = fmaf(wih[k4 * 4 + 0], xv.x, gi);
      gi = fmaf(wih[k4 * 4 + 1], xv.y, gi);
      gi = fmaf(wih[k4 * 4 + 2], xv.z, gi);
      gi = fmaf(wih[k4 * 4 + 3], xv.w, gi);
    }
#pragma unroll
    for (int k4 = 0; k4 < 32; ++k4) {
      float4 hv = *(const float4*)&h[k4 * 4];
      gh = fmaf(whh[k4 * 4 + 0], hv.x, gh);
      gh = fmaf(whh[k4 * 4 + 1], hv.y, gh);
      gh = fmaf(whh[k4 * 4 + 2], hv.z, gh);
      gh = fmaf(whh[k4 * 4 + 3], hv.w, gh);
    }
    gi_s[j] = gi;
    gh_s[j] = gh;
    __syncthreads();
    if (j < 128) {
      float r = 1.f / (1.f + expf(-(gi_s[j] + gh_s[j])));
      float z = 1.f / (1.f + expf(-(gi_s[128 + j] + gh_s[128 + j])));
      float nn = tanhf(gi_s[256 + j] + r * gh_s[256 + j]);
      h[j] = (1.f - z) * nn + z * h[j];
    }
    __syncthreads();
  }
  if (j < 128) red[j] = h[j] * fc_w[j];
  __syncthreads();
  for (int o = 64; o > 0; o >>= 1) {
    if (j < o) red[j] += red[j + o];
    __syncthreads();
  }
  if (j == 0) out[0] = red[0] + fc_b[0];
}

// ---------------- launch ----------------

extern "C" void kernel_launch(void* const* d_in, const int* in_sizes, int n_in,
                              void* d_out, int out_size, void* d_ws, size_t ws_size,
                              hipStream_t stream) {
  const float* x_seq = (const float*)d_in[0];
  const int*   ei    = (const int*)d_in[1];
  const float* W1    = (const float*)d_in[2];
  const float* b1    = (const float*)d_in[3];
  const float* W2    = (const float*)d_in[4];
  const float* b2    = (const float*)d_in[5];
  const float* w_ih  = (const float*)d_in[6];
  const float* w_hh  = (const float*)d_in[7];
  const float* b_ih  = (const float*)d_in[8];
  const float* b_hh  = (const float*)d_in[9];
  const float* fc_w  = (const float*)d_in[10];
  const float* fc_b  = (const float*)d_in[11];
  float* out = (float*)d_out;

  char* p = (char*)d_ws;
  size_t off = 0;
  auto carve = [&](size_t bytes) -> char* {
    char* q = p + off;
    off += (bytes + 255) & ~(size_t)255;
    return q;
  };
  int*   deg    = (int*)carve((size_t)NND * 4);
  float* dinv   = (float*)carve((size_t)NND * 4);
  int*   offs   = (int*)carve((size_t)NND * 4);
  int*   cursor = (int*)carve((size_t)NND * 4);
  int*   bsum   = (int*)carve(256 * 4);
  int*   boff   = (int*)carve(256 * 4);
  int*   csr    = (int*)carve((size_t)(NE + NND) * 4);
  float* xs4    = (float*)carve((size_t)NND * TT * 4 * 4);
  float* y      = (float*)carve((size_t)TT * NND * 3 * 4);
  __hip_bfloat16* h1s = (__hip_bfloat16*)carve((size_t)NND * 64 * 2);
  float* ppool  = (float*)carve((size_t)TT * 64 * 4);
  float* wihT   = (float*)carve((size_t)384 * 64 * 4);
  float* whhT   = (float*)carve((size_t)384 * 128 * 4);

  k_init<<<NBS, 256, 0, stream>>>(deg, ppool);
  k_deg<<<(NE + 255) / 256, 256, 0, stream>>>(ei, deg);
  k_dinv<<<NBS, 256, 0, stream>>>(deg, dinv);
  k_scan1<<<NBS, 256, 0, stream>>>(deg, bsum);
  k_scan2<<<1, 256, 0, stream>>>(bsum, boff);
  k_scan3<<<NBS, 256, 0, stream>>>(deg, boff, offs, cursor, csr);
  // 4 dst-range passes: csr write window per pass stays L2-resident
  for (int pp = 0; pp < 4; ++pp) {
    int lo = pp * (NND / 4), hi = (pp == 3) ? NND : (pp + 1) * (NND / 4);
    k_scatter<<<(NE + 255) / 256, 256, 0, stream>>>(ei, cursor, csr, lo, hi);
  }
  k_xs<<<(NND * TT * 4 + 255) / 256, 256, 0, stream>>>(x_seq, dinv, xs4);
  k_yagg<<<(NND * TT + 255) / 256, 256, 0, stream>>>(offs, deg, csr,
                                                     (const float4*)xs4, dinv, y);
  k_twih<<<(384 * 64 + 255) / 256, 256, 0, stream>>>(w_ih, wihT);
  k_twhh<<<(384 * 128 + 255) / 256, 256, 0, stream>>>(w_hh, whhT);

  for (int t = 0; t < TT; ++t) {
    k_h1<<<(NND * 64 + 255) / 256, 256, 0, stream>>>(y, W1, b1, dinv, h1s, t);
    k_aggemm<<<(NND + 127) / 128, 256, 0, stream>>>(offs, deg, csr, h1s, dinv,
                                                    W2, b2, ppool, t);
  }

  k_gru<<<1, 384, 0, stream>>>(ppool, wihT, whhT, b_ih, b_hh, fc_w, fc_b, out);
}

// Round 5
// 838.901 us; speedup vs baseline: 2.3065x; 2.3065x over previous
//
#include <hip/hip_runtime.h>
#include <hip/hip_bf16.h>

#define NND 50000
#define NE  1600000
#define TT  8
#define NBS ((NND + 255) / 256)   // 196 blocks over nodes

// ---------------- preprocessing ----------------

__global__ void k_init(int* __restrict__ deg, float* __restrict__ ppool) {
  int i = blockIdx.x * 256 + threadIdx.x;
  if (i < NND) deg[i] = 1;              // self-loop
  if (i < TT * 64) ppool[i] = 0.f;
}

__global__ void k_deg(const int* __restrict__ ei, int* __restrict__ deg) {
  int e = blockIdx.x * 256 + threadIdx.x;
  if (e < NE) atomicAdd(&deg[ei[NE + e]], 1);
}

__global__ void k_dinv(const int* __restrict__ deg, float* __restrict__ dinv) {
  int n = blockIdx.x * 256 + threadIdx.x;
  if (n < NND) dinv[n] = rsqrtf((float)deg[n]);
}

__global__ void k_scan1(const int* __restrict__ deg, int* __restrict__ bsum) {
  __shared__ int sh[256];
  int n = blockIdx.x * 256 + threadIdx.x;
  sh[threadIdx.x] = (n < NND) ? deg[n] : 0;
  __syncthreads();
  for (int o = 128; o > 0; o >>= 1) {
    if (threadIdx.x < o) sh[threadIdx.x] += sh[threadIdx.x + o];
    __syncthreads();
  }
  if (threadIdx.x == 0) bsum[blockIdx.x] = sh[0];
}

__global__ void k_scan2(const int* __restrict__ bsum, int* __restrict__ boff) {
  __shared__ int sh[256];
  int tid = threadIdx.x;
  int v = (tid < NBS) ? bsum[tid] : 0;
  sh[tid] = v;
  __syncthreads();
  for (int o = 1; o < 256; o <<= 1) {
    int t = (tid >= o) ? sh[tid - o] : 0;
    __syncthreads();
    sh[tid] += t;
    __syncthreads();
  }
  boff[tid] = sh[tid] - v;  // exclusive
}

__global__ void k_scan3(const int* __restrict__ deg, const int* __restrict__ boff,
                        int* __restrict__ offs, int* __restrict__ cursor,
                        int* __restrict__ csr) {
  __shared__ int sh[256];
  int tid = threadIdx.x;
  int n = blockIdx.x * 256 + tid;
  int v = (n < NND) ? deg[n] : 0;
  sh[tid] = v;
  __syncthreads();
  for (int o = 1; o < 256; o <<= 1) {
    int t2 = (tid >= o) ? sh[tid - o] : 0;
    __syncthreads();
    sh[tid] += t2;
    __syncthreads();
  }
  if (n < NND) {
    int x = boff[blockIdx.x] + sh[tid] - v;  // exclusive global offset
    offs[n] = x;
    cursor[n] = x + 1;   // slot 0 of each node = self-loop
    csr[x] = n;
  }
}

// dst-range-limited scatter pass: csr write window per pass ~1.65MB (fits L2),
// so dirty lines absorb all their writes before eviction.
__global__ void k_scatter(const int* __restrict__ ei, int* __restrict__ cursor,
                          int* __restrict__ csr, int lo, int hi) {
  int e = blockIdx.x * 256 + threadIdx.x;
  if (e < NE) {
    int d = ei[NE + e];
    if (d >= lo && d < hi) {
      int p = atomicAdd(&cursor[d], 1);
      csr[p] = ei[e];
    }
  }
}

// x_seq [T][N][3] -> xs4 [N][T][4] (padded, pre-scaled by dinv[n])
__global__ void k_xs(const float* __restrict__ x, const float* __restrict__ dinv,
                     float* __restrict__ xs4) {
  int g = blockIdx.x * 256 + threadIdx.x;
  if (g >= NND * TT * 4) return;
  int n = g >> 5, r = g & 31, t = r >> 2, c = r & 3;
  float v = 0.f;
  if (c < 3) v = x[(t * NND + n) * 3 + c] * dinv[n];
  xs4[g] = v;
}

// ---------------- layer 1 ----------------

// y[t][n][0..2] = dinv[n] * sum_{s in nbr(n)} xs[s][t][0..2]   (8 threads per node)
__global__ void k_yagg(const int* __restrict__ offs, const int* __restrict__ deg,
                       const int* __restrict__ csr, const float4* __restrict__ xs4,
                       const float* __restrict__ dinv, float* __restrict__ y) {
  int g = blockIdx.x * 256 + threadIdx.x;
  int n = g >> 3, t = g & 7;
  if (n >= NND) return;
  int o0 = offs[n], d = deg[n];
  float a0 = 0.f, a1 = 0.f, a2 = 0.f;
  int i = 0;
  for (; i + 2 <= d; i += 2) {
    int s0 = csr[o0 + i], s1 = csr[o0 + i + 1];
    float4 v0 = xs4[s0 * 8 + t];
    float4 v1 = xs4[s1 * 8 + t];
    a0 += v0.x + v1.x; a1 += v0.y + v1.y; a2 += v0.z + v1.z;
  }
  if (i < d) {
    float4 v = xs4[csr[o0 + i] * 8 + t];
    a0 += v.x; a1 += v.y; a2 += v.z;
  }
  float dn = dinv[n];
  size_t b = ((size_t)t * NND + n) * 3;
  y[b] = a0 * dn; y[b + 1] = a1 * dn; y[b + 2] = a2 * dn;
}

// h1s[n][c] = bf16( dinv[n] * relu(y[t][n]·W1[:,c] + b1[c]) )
__global__ void k_h1(const float* __restrict__ y, const float* __restrict__ W1,
                     const float* __restrict__ b1, const float* __restrict__ dinv,
                     __hip_bfloat16* __restrict__ h1s, int t) {
  int g = blockIdx.x * 256 + threadIdx.x;
  int n = g >> 6, c = g & 63;
  if (n >= NND) return;
  const float* yy = y + ((size_t)t * NND + n) * 3;
  float y0 = yy[0], y1 = yy[1], y2 = yy[2];
  float v = fmaf(y2, W1[128 + c], fmaf(y1, W1[64 + c], fmaf(y0, W1[c], b1[c])));
  h1s[g] = __float2bfloat16(fmaxf(v, 0.f) * dinv[n]);
}

// ---------------- layer 2 ----------------

// agg2[n][2cp..2cp+1] = dinv[n] * sum_nbr h1s[s][2cp..2cp+1]
// 32 lanes per node (2 nodes/wave), packed bf16x2 loads: 128B per neighbor row.
// High TLP restored: 25000 waves (round-4 fusion had 1564 -> 16% occupancy,
// latency-bound at 197us/dispatch).
__global__ void k_agg2(const int* __restrict__ offs, const int* __restrict__ deg,
                       const int* __restrict__ csr,
                       const unsigned int* __restrict__ h1s2,
                       const float* __restrict__ dinv, float2* __restrict__ agg2) {
  int g = blockIdx.x * 256 + threadIdx.x;   // NND*32 threads
  int n = g >> 5, cp = g & 31;
  if (n >= NND) return;
  int o0 = offs[n], d = deg[n];
  float a0 = 0.f, a1 = 0.f, b0 = 0.f, b1 = 0.f;
  int i = 0;
  for (; i + 4 <= d; i += 4) {
    int s0 = csr[o0 + i], s1 = csr[o0 + i + 1];
    int s2 = csr[o0 + i + 2], s3 = csr[o0 + i + 3];
    unsigned int v0 = h1s2[(size_t)s0 * 32 + cp];
    unsigned int v1 = h1s2[(size_t)s1 * 32 + cp];
    unsigned int v2 = h1s2[(size_t)s2 * 32 + cp];
    unsigned int v3 = h1s2[(size_t)s3 * 32 + cp];
    a0 += __uint_as_float(v0 << 16);  a1 += __uint_as_float(v0 & 0xffff0000u);
    b0 += __uint_as_float(v1 << 16);  b1 += __uint_as_float(v1 & 0xffff0000u);
    a0 += __uint_as_float(v2 << 16);  a1 += __uint_as_float(v2 & 0xffff0000u);
    b0 += __uint_as_float(v3 << 16);  b1 += __uint_as_float(v3 & 0xffff0000u);
  }
  for (; i < d; ++i) {
    unsigned int v = h1s2[(size_t)csr[o0 + i] * 32 + cp];
    a0 += __uint_as_float(v << 16);
    a1 += __uint_as_float(v & 0xffff0000u);
  }
  float dn = dinv[n];
  agg2[(size_t)n * 32 + cp] = make_float2((a0 + b0) * dn, (a1 + b1) * dn);
}

// C = agg2[N,64] @ W2[64,64]; pool += sum_rows relu(C + b2). Tile 128 rows/block.
__launch_bounds__(256)
__global__ void k_gemm_pool(const float* __restrict__ agg2, const float* __restrict__ W2,
                            const float* __restrict__ b2, float* __restrict__ ppool, int t) {
  __shared__ float As[128 * 64];   // 32 KB, chunk-swizzled
  __shared__ float Ws[64 * 64];    // 16 KB, W2^T, chunk-swizzled
  __shared__ float pool[64];
  int tid = threadIdx.x;
  int rows0 = blockIdx.x * 128;
  if (tid < 64) pool[tid] = 0.f;
  // Ws[j][swz(k)] = W2[k][j]
  for (int i = 0; i < 16; ++i) {
    int idx = i * 256 + tid;
    int k = idx >> 6, j = idx & 63;
    Ws[j * 64 + (((k >> 2) ^ ((j >> 3) & 7)) << 2) + (k & 3)] = W2[idx];
  }
  // As[row][swz(k)] = agg2[rows0+row][k]
  const float4* a4 = (const float4*)agg2;
  for (int i = 0; i < 8; ++i) {
    int idx4 = i * 256 + tid;          // [0, 2048)
    int row = idx4 >> 4, k4 = idx4 & 15;
    int grow = rows0 + row;
    float4 v = make_float4(0.f, 0.f, 0.f, 0.f);
    if (grow < NND) v = a4[grow * 16 + k4];
    *(float4*)&As[row * 64 + ((k4 ^ ((row >> 3) & 7)) << 2)] = v;
  }
  __syncthreads();

  int rowg = tid >> 3, colg = tid & 7;
  int r0 = rowg * 4, c0 = colg * 8;
  float acc[4][8];
  for (int a = 0; a < 4; ++a)
    for (int b = 0; b < 8; ++b) acc[a][b] = 0.f;
  for (int k4 = 0; k4 < 16; ++k4) {
    float4 w[8];
    for (int cc = 0; cc < 8; ++cc)
      w[cc] = *(const float4*)&Ws[(c0 + cc) * 64 + ((k4 ^ colg) << 2)];
    for (int rr = 0; rr < 4; ++rr) {
      int r = r0 + rr;
      float4 av = *(const float4*)&As[r * 64 + ((k4 ^ ((r >> 3) & 7)) << 2)];
      for (int cc = 0; cc < 8; ++cc) {
        acc[rr][cc] += av.x * w[cc].x;
        acc[rr][cc] += av.y * w[cc].y;
        acc[rr][cc] += av.z * w[cc].z;
        acc[rr][cc] += av.w * w[cc].w;
      }
    }
  }

  float b2c[8];
  for (int cc = 0; cc < 8; ++cc) b2c[cc] = b2[c0 + cc];
  float csum[8];
  for (int cc = 0; cc < 8; ++cc) csum[cc] = 0.f;
  for (int rr = 0; rr < 4; ++rr) {
    if (rows0 + r0 + rr < NND) {
      for (int cc = 0; cc < 8; ++cc)
        csum[cc] += fmaxf(acc[rr][cc] + b2c[cc], 0.f);
    }
  }
  for (int cc = 0; cc < 8; ++cc) atomicAdd(&pool[c0 + cc], csum[cc]);
  __syncthreads();
  if (tid < 64) atomicAdd(&ppool[t * 64 + tid], pool[tid]);
}

// ---------------- GRU + fc ----------------

__global__ void k_twih(const float* __restrict__ w, float* __restrict__ wt) {
  int g = blockIdx.x * 256 + threadIdx.x;
  if (g < 384 * 64) { int r = g >> 6, k = g & 63; wt[k * 384 + r] = w[g]; }
}
__global__ void k_twhh(const float* __restrict__ w, float* __restrict__ wt) {
  int g = blockIdx.x * 256 + threadIdx.x;
  if (g < 384 * 128) { int r = g >> 7, k = g & 127; wt[k * 384 + r] = w[g]; }
}

// One block, 384 threads: thread j owns gate-output j; weight columns in
// registers, loaded once.
__launch_bounds__(384, 2)
__global__ void k_gru(const float* __restrict__ ppool, const float* __restrict__ wihT,
                      const float* __restrict__ whhT, const float* __restrict__ b_ih,
                      const float* __restrict__ b_hh, const float* __restrict__ fc_w,
                      const float* __restrict__ fc_b, float* __restrict__ out) {
  __shared__ float x[64], h[128], gi_s[384], gh_s[384], red[128];
  int j = threadIdx.x;  // 0..383
  float wih[64];
#pragma unroll
  for (int k = 0; k < 64; ++k) wih[k] = wihT[k * 384 + j];
  float whh[128];
#pragma unroll
  for (int k = 0; k < 128; ++k) whh[k] = whhT[k * 384 + j];
  float bi = b_ih[j], bh = b_hh[j];
  if (j < 128) h[j] = 0.f;
  const float invn = 1.0f / (float)NND;
  for (int t = 0; t < TT; ++t) {
    if (j < 64) x[j] = ppool[t * 64 + j] * invn;
    __syncthreads();
    float gi = bi, gh = bh;
#pragma unroll
    for (int k4 = 0; k4 < 16; ++k4) {
      float4 xv = *(const float4*)&x[k4 * 4];
      gi = fmaf(wih[k4 * 4 + 0], xv.x, gi);
      gi = fmaf(wih[k4 * 4 + 1], xv.y, gi);
      gi = fmaf(wih[k4 * 4 + 2], xv.z, gi);
      gi = fmaf(wih[k4 * 4 + 3], xv.w, gi);
    }
#pragma unroll
    for (int k4 = 0; k4 < 32; ++k4) {
      float4 hv = *(const float4*)&h[k4 * 4];
      gh = fmaf(whh[k4 * 4 + 0], hv.x, gh);
      gh = fmaf(whh[k4 * 4 + 1], hv.y, gh);
      gh = fmaf(whh[k4 * 4 + 2], hv.z, gh);
      gh = fmaf(whh[k4 * 4 + 3], hv.w, gh);
    }
    gi_s[j] = gi;
    gh_s[j] = gh;
    __syncthreads();
    if (j < 128) {
      float r = 1.f / (1.f + expf(-(gi_s[j] + gh_s[j])));
      float z = 1.f / (1.f + expf(-(gi_s[128 + j] + gh_s[128 + j])));
      float nn = tanhf(gi_s[256 + j] + r * gh_s[256 + j]);
      h[j] = (1.f - z) * nn + z * h[j];
    }
    __syncthreads();
  }
  if (j < 128) red[j] = h[j] * fc_w[j];
  __syncthreads();
  for (int o = 64; o > 0; o >>= 1) {
    if (j < o) red[j] += red[j + o];
    __syncthreads();
  }
  if (j == 0) out[0] = red[0] + fc_b[0];
}

// ---------------- launch ----------------

extern "C" void kernel_launch(void* const* d_in, const int* in_sizes, int n_in,
                              void* d_out, int out_size, void* d_ws, size_t ws_size,
                              hipStream_t stream) {
  const float* x_seq = (const float*)d_in[0];
  const int*   ei    = (const int*)d_in[1];
  const float* W1    = (const float*)d_in[2];
  const float* b1    = (const float*)d_in[3];
  const float* W2    = (const float*)d_in[4];
  const float* b2    = (const float*)d_in[5];
  const float* w_ih  = (const float*)d_in[6];
  const float* w_hh  = (const float*)d_in[7];
  const float* b_ih  = (const float*)d_in[8];
  const float* b_hh  = (const float*)d_in[9];
  const float* fc_w  = (const float*)d_in[10];
  const float* fc_b  = (const float*)d_in[11];
  float* out = (float*)d_out;

  char* p = (char*)d_ws;
  size_t off = 0;
  auto carve = [&](size_t bytes) -> char* {
    char* q = p + off;
    off += (bytes + 255) & ~(size_t)255;
    return q;
  };
  int*   deg    = (int*)carve((size_t)NND * 4);
  float* dinv   = (float*)carve((size_t)NND * 4);
  int*   offs   = (int*)carve((size_t)NND * 4);
  int*   cursor = (int*)carve((size_t)NND * 4);
  int*   bsum   = (int*)carve(256 * 4);
  int*   boff   = (int*)carve(256 * 4);
  int*   csr    = (int*)carve((size_t)(NE + NND) * 4);
  float* xs4    = (float*)carve((size_t)NND * TT * 4 * 4);
  float* y      = (float*)carve((size_t)TT * NND * 3 * 4);
  __hip_bfloat16* h1s = (__hip_bfloat16*)carve((size_t)NND * 64 * 2);
  float* agg2   = (float*)carve((size_t)NND * 64 * 4);
  float* ppool  = (float*)carve((size_t)TT * 64 * 4);
  float* wihT   = (float*)carve((size_t)384 * 64 * 4);
  float* whhT   = (float*)carve((size_t)384 * 128 * 4);

  k_init<<<NBS, 256, 0, stream>>>(deg, ppool);
  k_deg<<<(NE + 255) / 256, 256, 0, stream>>>(ei, deg);
  k_dinv<<<NBS, 256, 0, stream>>>(deg, dinv);
  k_scan1<<<NBS, 256, 0, stream>>>(deg, bsum);
  k_scan2<<<1, 256, 0, stream>>>(bsum, boff);
  k_scan3<<<NBS, 256, 0, stream>>>(deg, boff, offs, cursor, csr);
  // 4 dst-range passes: csr write window per pass stays L2-resident
  for (int pp = 0; pp < 4; ++pp) {
    int lo = pp * (NND / 4), hi = (pp == 3) ? NND : (pp + 1) * (NND / 4);
    k_scatter<<<(NE + 255) / 256, 256, 0, stream>>>(ei, cursor, csr, lo, hi);
  }
  k_xs<<<(NND * TT * 4 + 255) / 256, 256, 0, stream>>>(x_seq, dinv, xs4);
  k_yagg<<<(NND * TT + 255) / 256, 256, 0, stream>>>(offs, deg, csr,
                                                     (const float4*)xs4, dinv, y);
  k_twih<<<(384 * 64 + 255) / 256, 256, 0, stream>>>(w_ih, wihT);
  k_twhh<<<(384 * 128 + 255) / 256, 256, 0, stream>>>(w_hh, whhT);

  for (int t = 0; t < TT; ++t) {
    k_h1<<<(NND * 64 + 255) / 256, 256, 0, stream>>>(y, W1, b1, dinv, h1s, t);
    k_agg2<<<(NND * 32 + 255) / 256, 256, 0, stream>>>(offs, deg, csr,
                                                       (const unsigned int*)h1s,
                                                       dinv, (float2*)agg2);
    k_gemm_pool<<<(NND + 127) / 128, 256, 0, stream>>>(agg2, W2, b2, ppool, t);
  }

  k_gru<<<1, 384, 0, stream>>>(ppool, wihT, whhT, b_ih, b_hh, fc_w, fc_b, out);
}

// Round 7
// 791.040 us; speedup vs baseline: 2.4460x; 1.0605x over previous
//
#include <hip/hip_runtime.h>
#include <hip/hip_fp8.h>

#define NND 50000
#define NE  1600000
#define TT  8
#define NBS ((NND + 255) / 256)   // 196 blocks over nodes

// ---------------- fp8 helpers ----------------

template <int I>
__device__ inline float fp8tof(unsigned int u) {
#if __has_builtin(__builtin_amdgcn_cvt_f32_fp8)
  return __builtin_amdgcn_cvt_f32_fp8(u, I);   // byte-select must be literal
#else
  __hip_fp8_e4m3 v; v.__x = (unsigned char)(u >> (I * 8)); return (float)v;
#endif
}

// ---------------- preprocessing ----------------

__global__ void k_init(int* __restrict__ deg, float* __restrict__ ppool) {
  int i = blockIdx.x * 256 + threadIdx.x;
  if (i < NND) deg[i] = 1;              // self-loop
  if (i < TT * 64) ppool[i] = 0.f;
}

// degree histogram; atomic old-value = unique slot rank for edge e (rank>=1,
// slot 0 per node = self-loop). Scatter then needs NO atomics.
__global__ void k_deg(const int* __restrict__ ei, int* __restrict__ deg,
                      int* __restrict__ rank) {
  int e = blockIdx.x * 256 + threadIdx.x;
  if (e < NE) rank[e] = atomicAdd(&deg[ei[NE + e]], 1);
}

__global__ void k_dinv(const int* __restrict__ deg, float* __restrict__ dinv) {
  int n = blockIdx.x * 256 + threadIdx.x;
  if (n < NND) dinv[n] = rsqrtf((float)deg[n]);
}

__global__ void k_scan1(const int* __restrict__ deg, int* __restrict__ bsum) {
  __shared__ int sh[256];
  int n = blockIdx.x * 256 + threadIdx.x;
  sh[threadIdx.x] = (n < NND) ? deg[n] : 0;
  __syncthreads();
  for (int o = 128; o > 0; o >>= 1) {
    if (threadIdx.x < o) sh[threadIdx.x] += sh[threadIdx.x + o];
    __syncthreads();
  }
  if (threadIdx.x == 0) bsum[blockIdx.x] = sh[0];
}

__global__ void k_scan2(const int* __restrict__ bsum, int* __restrict__ boff) {
  __shared__ int sh[256];
  int tid = threadIdx.x;
  int v = (tid < NBS) ? bsum[tid] : 0;
  sh[tid] = v;
  __syncthreads();
  for (int o = 1; o < 256; o <<= 1) {
    int t = (tid >= o) ? sh[tid - o] : 0;
    __syncthreads();
    sh[tid] += t;
    __syncthreads();
  }
  boff[tid] = sh[tid] - v;  // exclusive
}

__global__ void k_scan3(const int* __restrict__ deg, const int* __restrict__ boff,
                        int* __restrict__ offs, int* __restrict__ csr) {
  __shared__ int sh[256];
  int tid = threadIdx.x;
  int n = blockIdx.x * 256 + tid;
  int v = (n < NND) ? deg[n] : 0;
  sh[tid] = v;
  __syncthreads();
  for (int o = 1; o < 256; o <<= 1) {
    int t2 = (tid >= o) ? sh[tid - o] : 0;
    __syncthreads();
    sh[tid] += t2;
    __syncthreads();
  }
  if (n < NND) {
    int x = boff[blockIdx.x] + sh[tid] - v;  // exclusive global offset
    offs[n] = x;
    csr[x] = n;   // slot 0 = self-loop
  }
}

// atomic-free scatter, dst-range passes keep the csr write window L2-resident
__global__ void k_scatter(const int* __restrict__ ei, const int* __restrict__ offs,
                          const int* __restrict__ rank, int* __restrict__ csr,
                          int lo, int hi) {
  int e = blockIdx.x * 256 + threadIdx.x;
  if (e < NE) {
    int d = ei[NE + e];
    if (d >= lo && d < hi) csr[offs[d] + rank[e]] = ei[e];
  }
}

// x_seq [T][N][3] -> xs4 [N][T][4] (padded, pre-scaled by dinv[n])
__global__ void k_xs(const float* __restrict__ x, const float* __restrict__ dinv,
                     float* __restrict__ xs4) {
  int g = blockIdx.x * 256 + threadIdx.x;
  if (g >= NND * TT * 4) return;
  int n = g >> 5, r = g & 31, t = r >> 2, c = r & 3;
  float v = 0.f;
  if (c < 3) v = x[(t * NND + n) * 3 + c] * dinv[n];
  xs4[g] = v;
}

// ---------------- layer 1 ----------------

// y[t][n][0..2] = dinv[n] * sum_{s in nbr(n)} xs[s][t][0..2]   (8 threads per node)
__global__ void k_yagg(const int* __restrict__ offs, const int* __restrict__ deg,
                       const int* __restrict__ csr, const float4* __restrict__ xs4,
                       const float* __restrict__ dinv, float* __restrict__ y) {
  int g = blockIdx.x * 256 + threadIdx.x;
  int n = g >> 3, t = g & 7;
  if (n >= NND) return;
  int o0 = offs[n], d = deg[n];
  float a0 = 0.f, a1 = 0.f, a2 = 0.f;
  int i = 0;
  for (; i + 2 <= d; i += 2) {
    int s0 = csr[o0 + i], s1 = csr[o0 + i + 1];
    float4 v0 = xs4[s0 * 8 + t];
    float4 v1 = xs4[s1 * 8 + t];
    a0 += v0.x + v1.x; a1 += v0.y + v1.y; a2 += v0.z + v1.z;
  }
  if (i < d) {
    float4 v = xs4[csr[o0 + i] * 8 + t];
    a0 += v.x; a1 += v.y; a2 += v.z;
  }
  float dn = dinv[n];
  size_t b = ((size_t)t * NND + n) * 3;
  y[b] = a0 * dn; y[b + 1] = a1 * dn; y[b + 2] = a2 * dn;
}

// h1s8[n][c] = fp8_e4m3( dinv[n] * relu(y[t][n]·W1[:,c] + b1[c]) )
// fp8 shrinks the layer-2 gather working set to 3.2MB -> fits per-XCD L2 (4MB)
__global__ void k_h1(const float* __restrict__ y, const float* __restrict__ W1,
                     const float* __restrict__ b1, const float* __restrict__ dinv,
                     unsigned char* __restrict__ h1s8, int t) {
  int g = blockIdx.x * 256 + threadIdx.x;
  int n = g >> 6, c = g & 63;
  if (n >= NND) return;
  const float* yy = y + ((size_t)t * NND + n) * 3;
  float y0 = yy[0], y1 = yy[1], y2 = yy[2];
  float v = fmaf(y2, W1[128 + c], fmaf(y1, W1[64 + c], fmaf(y0, W1[c], b1[c])));
  __hip_fp8_e4m3 q(fmaxf(v, 0.f) * dinv[n]);
  h1s8[g] = (unsigned char)q.__x;
}

// ---------------- layer 2 ----------------

// agg2[n][4q..4q+3] = dinv[n] * sum_nbr fp8(h1s8[s][4q..4q+3])
// 16 lanes per node, uint loads: one 64B cache line per neighbor row.
__global__ void k_agg2(const int* __restrict__ offs, const int* __restrict__ deg,
                       const int* __restrict__ csr,
                       const unsigned int* __restrict__ h1s8u,
                       const float* __restrict__ dinv, float4* __restrict__ agg2) {
  int g = blockIdx.x * 256 + threadIdx.x;   // NND*16 threads
  int n = g >> 4, q = g & 15;
  if (n >= NND) return;
  int o0 = offs[n], d = deg[n];
  float a0 = 0.f, a1 = 0.f, a2 = 0.f, a3 = 0.f;
  int i = 0;
  for (; i + 2 <= d; i += 2) {
    unsigned int u0 = h1s8u[(size_t)csr[o0 + i] * 16 + q];
    unsigned int u1 = h1s8u[(size_t)csr[o0 + i + 1] * 16 + q];
    a0 += fp8tof<0>(u0); a1 += fp8tof<1>(u0); a2 += fp8tof<2>(u0); a3 += fp8tof<3>(u0);
    a0 += fp8tof<0>(u1); a1 += fp8tof<1>(u1); a2 += fp8tof<2>(u1); a3 += fp8tof<3>(u1);
  }
  if (i < d) {
    unsigned int u = h1s8u[(size_t)csr[o0 + i] * 16 + q];
    a0 += fp8tof<0>(u); a1 += fp8tof<1>(u); a2 += fp8tof<2>(u); a3 += fp8tof<3>(u);
  }
  float dn = dinv[n];
  agg2[(size_t)n * 16 + q] = make_float4(a0 * dn, a1 * dn, a2 * dn, a3 * dn);
}

// C = agg2[N,64] @ W2[64,64]; pool += sum_rows relu(C + b2). 64-row tiles (782 blocks).
__launch_bounds__(256)
__global__ void k_gemm_pool(const float* __restrict__ agg2, const float* __restrict__ W2,
                            const float* __restrict__ b2, float* __restrict__ ppool, int t) {
  __shared__ float As[64 * 64];    // 16 KB, chunk-swizzled
  __shared__ float Ws[64 * 64];    // 16 KB, W2^T, chunk-swizzled
  __shared__ float pool[64];
  int tid = threadIdx.x;
  int rows0 = blockIdx.x * 64;
  if (tid < 64) pool[tid] = 0.f;
  // Ws[j][swz(k)] = W2[k][j]
  for (int i = 0; i < 16; ++i) {
    int idx = i * 256 + tid;
    int k = idx >> 6, j = idx & 63;
    Ws[j * 64 + (((k >> 2) ^ ((j >> 3) & 7)) << 2) + (k & 3)] = W2[idx];
  }
  // As[row][swz(k)] = agg2[rows0+row][k]
  const float4* a4 = (const float4*)agg2;
  for (int i = 0; i < 4; ++i) {
    int idx4 = i * 256 + tid;          // [0, 1024)
    int row = idx4 >> 4, k4 = idx4 & 15;
    int grow = rows0 + row;
    float4 v = make_float4(0.f, 0.f, 0.f, 0.f);
    if (grow < NND) v = a4[(size_t)grow * 16 + k4];
    *(float4*)&As[row * 64 + ((k4 ^ ((row >> 3) & 7)) << 2)] = v;
  }
  __syncthreads();

  int rowg = tid >> 3, colg = tid & 7;
  int r0 = rowg * 2, c0 = colg * 8;
  float acc[2][8];
  for (int a = 0; a < 2; ++a)
    for (int b = 0; b < 8; ++b) acc[a][b] = 0.f;
  for (int k4 = 0; k4 < 16; ++k4) {
    float4 w[8];
    for (int cc = 0; cc < 8; ++cc)
      w[cc] = *(const float4*)&Ws[(c0 + cc) * 64 + ((k4 ^ colg) << 2)];
    for (int rr = 0; rr < 2; ++rr) {
      int r = r0 + rr;
      float4 av = *(const float4*)&As[r * 64 + ((k4 ^ ((r >> 3) & 7)) << 2)];
      for (int cc = 0; cc < 8; ++cc) {
        acc[rr][cc] += av.x * w[cc].x;
        acc[rr][cc] += av.y * w[cc].y;
        acc[rr][cc] += av.z * w[cc].z;
        acc[rr][cc] += av.w * w[cc].w;
      }
    }
  }

  float b2c[8];
  for (int cc = 0; cc < 8; ++cc) b2c[cc] = b2[c0 + cc];
  float csum[8];
  for (int cc = 0; cc < 8; ++cc) csum[cc] = 0.f;
  for (int rr = 0; rr < 2; ++rr) {
    if (rows0 + r0 + rr < NND) {
      for (int cc = 0; cc < 8; ++cc)
        csum[cc] += fmaxf(acc[rr][cc] + b2c[cc], 0.f);
    }
  }
  for (int cc = 0; cc < 8; ++cc) atomicAdd(&pool[c0 + cc], csum[cc]);
  __syncthreads();
  if (tid < 64) atomicAdd(&ppool[t * 64 + tid], pool[tid]);
}

// ---------------- GRU + fc ----------------

__global__ void k_twih(const float* __restrict__ w, float* __restrict__ wt) {
  int g = blockIdx.x * 256 + threadIdx.x;
  if (g < 384 * 64) { int r = g >> 6, k = g & 63; wt[k * 384 + r] = w[g]; }
}
__global__ void k_twhh(const float* __restrict__ w, float* __restrict__ wt) {
  int g = blockIdx.x * 256 + threadIdx.x;
  if (g < 384 * 128) { int r = g >> 7, k = g & 127; wt[k * 384 + r] = w[g]; }
}

// One block, 384 threads: thread j owns gate-output j; weight columns in
// registers, loaded once.
__launch_bounds__(384, 2)
__global__ void k_gru(const float* __restrict__ ppool, const float* __restrict__ wihT,
                      const float* __restrict__ whhT, const float* __restrict__ b_ih,
                      const float* __restrict__ b_hh, const float* __restrict__ fc_w,
                      const float* __restrict__ fc_b, float* __restrict__ out) {
  __shared__ float x[64], h[128], gi_s[384], gh_s[384], red[128];
  int j = threadIdx.x;  // 0..383
  float wih[64];
#pragma unroll
  for (int k = 0; k < 64; ++k) wih[k] = wihT[k * 384 + j];
  float whh[128];
#pragma unroll
  for (int k = 0; k < 128; ++k) whh[k] = whhT[k * 384 + j];
  float bi = b_ih[j], bh = b_hh[j];
  if (j < 128) h[j] = 0.f;
  const float invn = 1.0f / (float)NND;
  for (int t = 0; t < TT; ++t) {
    if (j < 64) x[j] = ppool[t * 64 + j] * invn;
    __syncthreads();
    float gi = bi, gh = bh;
#pragma unroll
    for (int k4 = 0; k4 < 16; ++k4) {
      float4 xv = *(const float4*)&x[k4 * 4];
      gi = fmaf(wih[k4 * 4 + 0], xv.x, gi);
      gi = fmaf(wih[k4 * 4 + 1], xv.y, gi);
      gi = fmaf(wih[k4 * 4 + 2], xv.z, gi);
      gi = fmaf(wih[k4 * 4 + 3], xv.w, gi);
    }
#pragma unroll
    for (int k4 = 0; k4 < 32; ++k4) {
      float4 hv = *(const float4*)&h[k4 * 4];
      gh = fmaf(whh[k4 * 4 + 0], hv.x, gh);
      gh = fmaf(whh[k4 * 4 + 1], hv.y, gh);
      gh = fmaf(whh[k4 * 4 + 2], hv.z, gh);
      gh = fmaf(whh[k4 * 4 + 3], hv.w, gh);
    }
    gi_s[j] = gi;
    gh_s[j] = gh;
    __syncthreads();
    if (j < 128) {
      float r = 1.f / (1.f + expf(-(gi_s[j] + gh_s[j])));
      float z = 1.f / (1.f + expf(-(gi_s[128 + j] + gh_s[128 + j])));
      float nn = tanhf(gi_s[256 + j] + r * gh_s[256 + j]);
      h[j] = (1.f - z) * nn + z * h[j];
    }
    __syncthreads();
  }
  if (j < 128) red[j] = h[j] * fc_w[j];
  __syncthreads();
  for (int o = 64; o > 0; o >>= 1) {
    if (j < o) red[j] += red[j + o];
    __syncthreads();
  }
  if (j == 0) out[0] = red[0] + fc_b[0];
}

// ---------------- launch ----------------

extern "C" void kernel_launch(void* const* d_in, const int* in_sizes, int n_in,
                              void* d_out, int out_size, void* d_ws, size_t ws_size,
                              hipStream_t stream) {
  const float* x_seq = (const float*)d_in[0];
  const int*   ei    = (const int*)d_in[1];
  const float* W1    = (const float*)d_in[2];
  const float* b1    = (const float*)d_in[3];
  const float* W2    = (const float*)d_in[4];
  const float* b2    = (const float*)d_in[5];
  const float* w_ih  = (const float*)d_in[6];
  const float* w_hh  = (const float*)d_in[7];
  const float* b_ih  = (const float*)d_in[8];
  const float* b_hh  = (const float*)d_in[9];
  const float* fc_w  = (const float*)d_in[10];
  const float* fc_b  = (const float*)d_in[11];
  float* out = (float*)d_out;

  char* p = (char*)d_ws;
  size_t off = 0;
  auto carve = [&](size_t bytes) -> char* {
    char* q = p + off;
    off += (bytes + 255) & ~(size_t)255;
    return q;
  };
  int*   deg    = (int*)carve((size_t)NND * 4);
  float* dinv   = (float*)carve((size_t)NND * 4);
  int*   offs   = (int*)carve((size_t)NND * 4);
  int*   bsum   = (int*)carve(256 * 4);
  int*   boff   = (int*)carve(256 * 4);
  int*   rank   = (int*)carve((size_t)NE * 4);
  int*   csr    = (int*)carve((size_t)(NE + NND) * 4);
  float* xs4    = (float*)carve((size_t)NND * TT * 4 * 4);
  float* y      = (float*)carve((size_t)TT * NND * 3 * 4);
  unsigned char* h1s8 = (unsigned char*)carve((size_t)NND * 64);
  float* agg2   = (float*)carve((size_t)NND * 64 * 4);
  float* ppool  = (float*)carve((size_t)TT * 64 * 4);
  float* wihT   = (float*)carve((size_t)384 * 64 * 4);
  float* whhT   = (float*)carve((size_t)384 * 128 * 4);

  k_init<<<NBS, 256, 0, stream>>>(deg, ppool);
  k_deg<<<(NE + 255) / 256, 256, 0, stream>>>(ei, deg, rank);
  k_dinv<<<NBS, 256, 0, stream>>>(deg, dinv);
  k_scan1<<<NBS, 256, 0, stream>>>(deg, bsum);
  k_scan2<<<1, 256, 0, stream>>>(bsum, boff);
  k_scan3<<<NBS, 256, 0, stream>>>(deg, boff, offs, csr);
  // 4 atomic-free dst-range passes: csr write window per pass stays L2-resident
  for (int pp = 0; pp < 4; ++pp) {
    int lo = pp * (NND / 4), hi = (pp == 3) ? NND : (pp + 1) * (NND / 4);
    k_scatter<<<(NE + 255) / 256, 256, 0, stream>>>(ei, offs, rank, csr, lo, hi);
  }
  k_xs<<<(NND * TT * 4 + 255) / 256, 256, 0, stream>>>(x_seq, dinv, xs4);
  k_yagg<<<(NND * TT + 255) / 256, 256, 0, stream>>>(offs, deg, csr,
                                                     (const float4*)xs4, dinv, y);
  k_twih<<<(384 * 64 + 255) / 256, 256, 0, stream>>>(w_ih, wihT);
  k_twhh<<<(384 * 128 + 255) / 256, 256, 0, stream>>>(w_hh, whhT);

  for (int t = 0; t < TT; ++t) {
    k_h1<<<(NND * 64 + 255) / 256, 256, 0, stream>>>(y, W1, b1, dinv, h1s8, t);
    k_agg2<<<(NND * 16 + 255) / 256, 256, 0, stream>>>(offs, deg, csr,
                                                       (const unsigned int*)h1s8,
                                                       dinv, (float4*)agg2);
    k_gemm_pool<<<(NND + 63) / 64, 256, 0, stream>>>(agg2, W2, b2, ppool, t);
  }

  k_gru<<<1, 384, 0, stream>>>(ppool, wihT, whhT, b_ih, b_hh, fc_w, fc_b, out);
}

// Round 8
// 657.379 us; speedup vs baseline: 2.9434x; 1.2033x over previous
//
#include <hip/hip_runtime.h>
#include <hip/hip_fp8.h>
#include <hip/hip_bf16.h>

#define NND 50000
#define NE  1600000
#define TT  8
#define NBS ((NND + 255) / 256)   // 196 blocks over nodes

// ---------------- fp8 / bf16 helpers ----------------

template <int I>
__device__ inline float fp8tof(unsigned int u) {
#if __has_builtin(__builtin_amdgcn_cvt_f32_fp8)
  return __builtin_amdgcn_cvt_f32_fp8(u, I);   // byte-select must be literal
#else
  __hip_fp8_e4m3 v; v.__x = (unsigned char)(u >> (I * 8)); return (float)v;
#endif
}

__device__ inline unsigned int pk4_fp8(float a, float b, float c, float d) {
#if __has_builtin(__builtin_amdgcn_cvt_pk_fp8_f32)
  int v = 0;
  v = __builtin_amdgcn_cvt_pk_fp8_f32(a, b, v, false);  // bytes 0,1
  v = __builtin_amdgcn_cvt_pk_fp8_f32(c, d, v, true);   // bytes 2,3
  return (unsigned int)v;
#else
  __hip_fp8_e4m3 qa(a), qb(b), qc(c), qd(d);
  return (unsigned int)qa.__x | ((unsigned int)qb.__x << 8) |
         ((unsigned int)qc.__x << 16) | ((unsigned int)qd.__x << 24);
#endif
}

__device__ inline unsigned int pkbf(float a, float b) {
  __hip_bfloat16 ha = __float2bfloat16(a), hb = __float2bfloat16(b);
  unsigned short ua = *(unsigned short*)&ha, ub = *(unsigned short*)&hb;
  return (unsigned int)ua | ((unsigned int)ub << 16);
}
__device__ inline float bl(unsigned int w) { return __uint_as_float(w << 16); }
__device__ inline float bh(unsigned int w) { return __uint_as_float(w & 0xffff0000u); }

// ---------------- preprocessing ----------------

__global__ void k_init(int* __restrict__ deg, float* __restrict__ ppool) {
  int i = blockIdx.x * 256 + threadIdx.x;
  if (i < NND) deg[i] = 1;              // self-loop
  if (i < TT * 64) ppool[i] = 0.f;
}

// degree histogram; atomic old-value = unique slot rank (>=1; slot 0 = self-loop)
__global__ void k_deg(const int* __restrict__ ei, int* __restrict__ deg,
                      int* __restrict__ rank) {
  int e = blockIdx.x * 256 + threadIdx.x;
  if (e < NE) rank[e] = atomicAdd(&deg[ei[NE + e]], 1);
}

__global__ void k_dinv(const int* __restrict__ deg, float* __restrict__ dinv) {
  int n = blockIdx.x * 256 + threadIdx.x;
  if (n < NND) dinv[n] = rsqrtf((float)deg[n]);
}

__global__ void k_scan1(const int* __restrict__ deg, int* __restrict__ bsum) {
  __shared__ int sh[256];
  int n = blockIdx.x * 256 + threadIdx.x;
  sh[threadIdx.x] = (n < NND) ? deg[n] : 0;
  __syncthreads();
  for (int o = 128; o > 0; o >>= 1) {
    if (threadIdx.x < o) sh[threadIdx.x] += sh[threadIdx.x + o];
    __syncthreads();
  }
  if (threadIdx.x == 0) bsum[blockIdx.x] = sh[0];
}

__global__ void k_scan2(const int* __restrict__ bsum, int* __restrict__ boff) {
  __shared__ int sh[256];
  int tid = threadIdx.x;
  int v = (tid < NBS) ? bsum[tid] : 0;
  sh[tid] = v;
  __syncthreads();
  for (int o = 1; o < 256; o <<= 1) {
    int t = (tid >= o) ? sh[tid - o] : 0;
    __syncthreads();
    sh[tid] += t;
    __syncthreads();
  }
  boff[tid] = sh[tid] - v;  // exclusive
}

__global__ void k_scan3(const int* __restrict__ deg, const int* __restrict__ boff,
                        int* __restrict__ offs, int* __restrict__ csr) {
  __shared__ int sh[256];
  int tid = threadIdx.x;
  int n = blockIdx.x * 256 + tid;
  int v = (n < NND) ? deg[n] : 0;
  sh[tid] = v;
  __syncthreads();
  for (int o = 1; o < 256; o <<= 1) {
    int t2 = (tid >= o) ? sh[tid - o] : 0;
    __syncthreads();
    sh[tid] += t2;
    __syncthreads();
  }
  if (n < NND) {
    int x = boff[blockIdx.x] + sh[tid] - v;  // exclusive global offset
    offs[n] = x;
    csr[x] = n;   // slot 0 = self-loop
  }
}

// atomic-free scatter; 2 dst-range passes keep the csr write window L2-resident
__global__ void k_scatter(const int* __restrict__ ei, const int* __restrict__ offs,
                          const int* __restrict__ rank, int* __restrict__ csr,
                          int lo, int hi) {
  int e = blockIdx.x * 256 + threadIdx.x;
  if (e < NE) {
    int d = ei[NE + e];
    if (d >= lo && d < hi) csr[offs[d] + rank[e]] = ei[e];
  }
}

// x_seq [T][N][3] f32 -> xs2 [N][T] uint2 (4 bf16: x0,x1,x2,pad, pre-scaled by dinv)
// 64B per node line -> layer-1 gather is 1 line/neighbor; 3.2MB total (L2-fit)
__global__ void k_xsb(const float* __restrict__ x, const float* __restrict__ dinv,
                      uint2* __restrict__ xs2) {
  int g = blockIdx.x * 256 + threadIdx.x;
  if (g >= NND * TT) return;
  int n = g >> 3, t = g & 7;
  const float* xx = x + ((size_t)t * NND + n) * 3;
  float dn = dinv[n];
  xs2[(size_t)n * 8 + t] = make_uint2(pkbf(xx[0] * dn, xx[1] * dn),
                                      pkbf(xx[2] * dn, 0.f));
}

// ---------------- fused layer 1: aggregate + W1 + ReLU + fp8 pack, ALL t ----------------

// thread (n,t): gather neighbor bf16 x-rows (8B/lane, 64B line per node visit,
// unroll-4 for MLP), then write h1all[t][n][64] fp8 (4x uint4 stores).
__global__ void k_yh1(const int* __restrict__ offs, const int* __restrict__ deg,
                      const int* __restrict__ csr, const uint2* __restrict__ xs2,
                      const float* __restrict__ dinv, const float* __restrict__ W1,
                      const float* __restrict__ b1, uint4* __restrict__ h1w) {
  int g = blockIdx.x * 256 + threadIdx.x;
  int n = g >> 3, t = g & 7;
  if (n >= NND) return;
  int o0 = offs[n], d = deg[n];
  float a0 = 0.f, a1 = 0.f, a2 = 0.f;
  int i = 0;
  for (; i + 4 <= d; i += 4) {
    int s0 = csr[o0 + i], s1 = csr[o0 + i + 1];
    int s2 = csr[o0 + i + 2], s3 = csr[o0 + i + 3];
    uint2 u0 = xs2[(size_t)s0 * 8 + t];
    uint2 u1 = xs2[(size_t)s1 * 8 + t];
    uint2 u2 = xs2[(size_t)s2 * 8 + t];
    uint2 u3 = xs2[(size_t)s3 * 8 + t];
    a0 += bl(u0.x) + bl(u1.x) + bl(u2.x) + bl(u3.x);
    a1 += bh(u0.x) + bh(u1.x) + bh(u2.x) + bh(u3.x);
    a2 += bl(u0.y) + bl(u1.y) + bl(u2.y) + bl(u3.y);
  }
  for (; i < d; ++i) {
    uint2 u = xs2[(size_t)csr[o0 + i] * 8 + t];
    a0 += bl(u.x); a1 += bh(u.x); a2 += bl(u.y);
  }
  float dn = dinv[n];
  float y0 = a0 * dn, y1 = a1 * dn, y2 = a2 * dn;
  size_t base = ((size_t)t * NND + n) * 4;
#pragma unroll
  for (int k = 0; k < 4; ++k) {
    float vv[16];
#pragma unroll
    for (int m = 0; m < 16; ++m) {
      int c = k * 16 + m;
      float hv = fmaf(y2, W1[128 + c], fmaf(y1, W1[64 + c], fmaf(y0, W1[c], b1[c])));
      vv[m] = fmaxf(hv, 0.f) * dn;
    }
    uint4 o;
    o.x = pk4_fp8(vv[0], vv[1], vv[2], vv[3]);
    o.y = pk4_fp8(vv[4], vv[5], vv[6], vv[7]);
    o.z = pk4_fp8(vv[8], vv[9], vv[10], vv[11]);
    o.w = pk4_fp8(vv[12], vv[13], vv[14], vv[15]);
    h1w[base + k] = o;
  }
}

// ---------------- layer 2 ----------------

#define ACC16(u) do { \
  acc[0]  += fp8tof<0>((u).x); acc[1]  += fp8tof<1>((u).x); acc[2]  += fp8tof<2>((u).x); acc[3]  += fp8tof<3>((u).x); \
  acc[4]  += fp8tof<0>((u).y); acc[5]  += fp8tof<1>((u).y); acc[6]  += fp8tof<2>((u).y); acc[7]  += fp8tof<3>((u).y); \
  acc[8]  += fp8tof<0>((u).z); acc[9]  += fp8tof<1>((u).z); acc[10] += fp8tof<2>((u).z); acc[11] += fp8tof<3>((u).z); \
  acc[12] += fp8tof<0>((u).w); acc[13] += fp8tof<1>((u).w); acc[14] += fp8tof<2>((u).w); acc[15] += fp8tof<3>((u).w); \
} while (0)

// 4 lanes/node, uint4 (16 fp8) per lane: 16 lines in flight per wave-instruction,
// unroll-4 -> 4 outstanding loads/thread. (Round-7 version: 16 lanes/node, uint,
// unroll-2 -> MLP-starved at ~60us/dispatch.)
__global__ void k_agg2(const int* __restrict__ offs, const int* __restrict__ deg,
                       const int* __restrict__ csr, const uint4* __restrict__ h1v,
                       const float* __restrict__ dinv, float4* __restrict__ agg2) {
  int g = blockIdx.x * 256 + threadIdx.x;   // NND*4 threads
  int n = g >> 2, q = g & 3;
  if (n >= NND) return;
  int o0 = offs[n], d = deg[n];
  float acc[16];
#pragma unroll
  for (int m = 0; m < 16; ++m) acc[m] = 0.f;
  int i = 0;
  for (; i + 4 <= d; i += 4) {
    int s0 = csr[o0 + i], s1 = csr[o0 + i + 1];
    int s2 = csr[o0 + i + 2], s3 = csr[o0 + i + 3];
    uint4 u0 = h1v[(size_t)s0 * 4 + q];
    uint4 u1 = h1v[(size_t)s1 * 4 + q];
    uint4 u2 = h1v[(size_t)s2 * 4 + q];
    uint4 u3 = h1v[(size_t)s3 * 4 + q];
    ACC16(u0); ACC16(u1); ACC16(u2); ACC16(u3);
  }
  for (; i < d; ++i) {
    uint4 u = h1v[(size_t)csr[o0 + i] * 4 + q];
    ACC16(u);
  }
  float dn = dinv[n];
  float4* out = agg2 + (size_t)n * 16 + q * 4;
  out[0] = make_float4(acc[0] * dn,  acc[1] * dn,  acc[2] * dn,  acc[3] * dn);
  out[1] = make_float4(acc[4] * dn,  acc[5] * dn,  acc[6] * dn,  acc[7] * dn);
  out[2] = make_float4(acc[8] * dn,  acc[9] * dn,  acc[10] * dn, acc[11] * dn);
  out[3] = make_float4(acc[12] * dn, acc[13] * dn, acc[14] * dn, acc[15] * dn);
}

// C = agg2[N,64] @ W2[64,64]; pool += sum_rows relu(C + b2). 64-row tiles (782 blocks).
__launch_bounds__(256)
__global__ void k_gemm_pool(const float* __restrict__ agg2, const float* __restrict__ W2,
                            const float* __restrict__ b2, float* __restrict__ ppool, int t) {
  __shared__ float As[64 * 64];    // 16 KB, chunk-swizzled
  __shared__ float Ws[64 * 64];    // 16 KB, W2^T, chunk-swizzled
  __shared__ float pool[64];
  int tid = threadIdx.x;
  int rows0 = blockIdx.x * 64;
  if (tid < 64) pool[tid] = 0.f;
  for (int i = 0; i < 16; ++i) {
    int idx = i * 256 + tid;
    int k = idx >> 6, j = idx & 63;
    Ws[j * 64 + (((k >> 2) ^ ((j >> 3) & 7)) << 2) + (k & 3)] = W2[idx];
  }
  const float4* a4 = (const float4*)agg2;
  for (int i = 0; i < 4; ++i) {
    int idx4 = i * 256 + tid;          // [0, 1024)
    int row = idx4 >> 4, k4 = idx4 & 15;
    int grow = rows0 + row;
    float4 v = make_float4(0.f, 0.f, 0.f, 0.f);
    if (grow < NND) v = a4[(size_t)grow * 16 + k4];
    *(float4*)&As[row * 64 + ((k4 ^ ((row >> 3) & 7)) << 2)] = v;
  }
  __syncthreads();

  int rowg = tid >> 3, colg = tid & 7;
  int r0 = rowg * 2, c0 = colg * 8;
  float acc[2][8];
  for (int a = 0; a < 2; ++a)
    for (int b = 0; b < 8; ++b) acc[a][b] = 0.f;
  for (int k4 = 0; k4 < 16; ++k4) {
    float4 w[8];
    for (int cc = 0; cc < 8; ++cc)
      w[cc] = *(const float4*)&Ws[(c0 + cc) * 64 + ((k4 ^ colg) << 2)];
    for (int rr = 0; rr < 2; ++rr) {
      int r = r0 + rr;
      float4 av = *(const float4*)&As[r * 64 + ((k4 ^ ((r >> 3) & 7)) << 2)];
      for (int cc = 0; cc < 8; ++cc) {
        acc[rr][cc] += av.x * w[cc].x;
        acc[rr][cc] += av.y * w[cc].y;
        acc[rr][cc] += av.z * w[cc].z;
        acc[rr][cc] += av.w * w[cc].w;
      }
    }
  }

  float b2c[8];
  for (int cc = 0; cc < 8; ++cc) b2c[cc] = b2[c0 + cc];
  float csum[8];
  for (int cc = 0; cc < 8; ++cc) csum[cc] = 0.f;
  for (int rr = 0; rr < 2; ++rr) {
    if (rows0 + r0 + rr < NND) {
      for (int cc = 0; cc < 8; ++cc)
        csum[cc] += fmaxf(acc[rr][cc] + b2c[cc], 0.f);
    }
  }
  for (int cc = 0; cc < 8; ++cc) atomicAdd(&pool[c0 + cc], csum[cc]);
  __syncthreads();
  if (tid < 64) atomicAdd(&ppool[t * 64 + tid], pool[tid]);
}

// ---------------- GRU + fc ----------------

__global__ void k_twih(const float* __restrict__ w, float* __restrict__ wt) {
  int g = blockIdx.x * 256 + threadIdx.x;
  if (g < 384 * 64) { int r = g >> 6, k = g & 63; wt[k * 384 + r] = w[g]; }
}
__global__ void k_twhh(const float* __restrict__ w, float* __restrict__ wt) {
  int g = blockIdx.x * 256 + threadIdx.x;
  if (g < 384 * 128) { int r = g >> 7, k = g & 127; wt[k * 384 + r] = w[g]; }
}

__launch_bounds__(384, 2)
__global__ void k_gru(const float* __restrict__ ppool, const float* __restrict__ wihT,
                      const float* __restrict__ whhT, const float* __restrict__ b_ih,
                      const float* __restrict__ b_hh, const float* __restrict__ fc_w,
                      const float* __restrict__ fc_b, float* __restrict__ out) {
  __shared__ float x[64], h[128], gi_s[384], gh_s[384], red[128];
  int j = threadIdx.x;  // 0..383
  float wih[64];
#pragma unroll
  for (int k = 0; k < 64; ++k) wih[k] = wihT[k * 384 + j];
  float whh[128];
#pragma unroll
  for (int k = 0; k < 128; ++k) whh[k] = whhT[k * 384 + j];
  float bi = b_ih[j], bh2 = b_hh[j];
  if (j < 128) h[j] = 0.f;
  const float invn = 1.0f / (float)NND;
  for (int t = 0; t < TT; ++t) {
    if (j < 64) x[j] = ppool[t * 64 + j] * invn;
    __syncthreads();
    float gi = bi, gh = bh2;
#pragma unroll
    for (int k4 = 0; k4 < 16; ++k4) {
      float4 xv = *(const float4*)&x[k4 * 4];
      gi = fmaf(wih[k4 * 4 + 0], xv.x, gi);
      gi = fmaf(wih[k4 * 4 + 1], xv.y, gi);
      gi = fmaf(wih[k4 * 4 + 2], xv.z, gi);
      gi = fmaf(wih[k4 * 4 + 3], xv.w, gi);
    }
#pragma unroll
    for (int k4 = 0; k4 < 32; ++k4) {
      float4 hv = *(const float4*)&h[k4 * 4];
      gh = fmaf(whh[k4 * 4 + 0], hv.x, gh);
      gh = fmaf(whh[k4 * 4 + 1], hv.y, gh);
      gh = fmaf(whh[k4 * 4 + 2], hv.z, gh);
      gh = fmaf(whh[k4 * 4 + 3], hv.w, gh);
    }
    gi_s[j] = gi;
    gh_s[j] = gh;
    __syncthreads();
    if (j < 128) {
      float r = 1.f / (1.f + expf(-(gi_s[j] + gh_s[j])));
      float z = 1.f / (1.f + expf(-(gi_s[128 + j] + gh_s[128 + j])));
      float nn = tanhf(gi_s[256 + j] + r * gh_s[256 + j]);
      h[j] = (1.f - z) * nn + z * h[j];
    }
    __syncthreads();
  }
  if (j < 128) red[j] = h[j] * fc_w[j];
  __syncthreads();
  for (int o = 64; o > 0; o >>= 1) {
    if (j < o) red[j] += red[j + o];
    __syncthreads();
  }
  if (j == 0) out[0] = red[0] + fc_b[0];
}

// ---------------- launch ----------------

extern "C" void kernel_launch(void* const* d_in, const int* in_sizes, int n_in,
                              void* d_out, int out_size, void* d_ws, size_t ws_size,
                              hipStream_t stream) {
  const float* x_seq = (const float*)d_in[0];
  const int*   ei    = (const int*)d_in[1];
  const float* W1    = (const float*)d_in[2];
  const float* b1    = (const float*)d_in[3];
  const float* W2    = (const float*)d_in[4];
  const float* b2    = (const float*)d_in[5];
  const float* w_ih  = (const float*)d_in[6];
  const float* w_hh  = (const float*)d_in[7];
  const float* b_ih  = (const float*)d_in[8];
  const float* b_hh  = (const float*)d_in[9];
  const float* fc_w  = (const float*)d_in[10];
  const float* fc_b  = (const float*)d_in[11];
  float* out = (float*)d_out;

  char* p = (char*)d_ws;
  size_t off = 0;
  auto carve = [&](size_t bytes) -> char* {
    char* q = p + off;
    off += (bytes + 255) & ~(size_t)255;
    return q;
  };
  int*   deg    = (int*)carve((size_t)NND * 4);
  float* dinv   = (float*)carve((size_t)NND * 4);
  int*   offs   = (int*)carve((size_t)NND * 4);
  int*   bsum   = (int*)carve(256 * 4);
  int*   boff   = (int*)carve(256 * 4);
  int*   csr    = (int*)carve((size_t)(NE + NND) * 4);
  uint2* xs2    = (uint2*)carve((size_t)NND * 8 * 8);        // 3.2 MB
  float* agg2   = (float*)carve((size_t)NND * 64 * 4);       // 12.8 MB
  float* ppool  = (float*)carve((size_t)TT * 64 * 4);
  float* wihT   = (float*)carve((size_t)384 * 64 * 4);
  float* whhT   = (float*)carve((size_t)384 * 128 * 4);
  char*  tail   = carve((size_t)TT * NND * 64);              // 25.6 MB: h1all
  uint4* h1all  = (uint4*)tail;
  int*   rank   = (int*)tail;   // alias: rank dead before h1all's first write

  k_init<<<NBS, 256, 0, stream>>>(deg, ppool);
  k_deg<<<(NE + 255) / 256, 256, 0, stream>>>(ei, deg, rank);
  k_dinv<<<NBS, 256, 0, stream>>>(deg, dinv);
  k_scan1<<<NBS, 256, 0, stream>>>(deg, bsum);
  k_scan2<<<1, 256, 0, stream>>>(bsum, boff);
  k_scan3<<<NBS, 256, 0, stream>>>(deg, boff, offs, csr);
  // 2 atomic-free dst-range passes (csr window ~3.3MB, L2-resident)
  for (int pp = 0; pp < 2; ++pp) {
    int lo = pp * (NND / 2), hi = (pp == 1) ? NND : (NND / 2);
    k_scatter<<<(NE + 255) / 256, 256, 0, stream>>>(ei, offs, rank, csr, lo, hi);
  }
  k_xsb<<<(NND * TT + 255) / 256, 256, 0, stream>>>(x_seq, dinv, xs2);
  k_twih<<<(384 * 64 + 255) / 256, 256, 0, stream>>>(w_ih, wihT);
  k_twhh<<<(384 * 128 + 255) / 256, 256, 0, stream>>>(w_hh, whhT);
  // fused layer-1 for all t (rank is dead from here; h1all reuses its space)
  k_yh1<<<(NND * TT + 255) / 256, 256, 0, stream>>>(offs, deg, csr, xs2, dinv,
                                                    W1, b1, h1all);

  for (int t = 0; t < TT; ++t) {
    const uint4* h1v = h1all + (size_t)t * NND * 4;
    k_agg2<<<(NND * 4 + 255) / 256, 256, 0, stream>>>(offs, deg, csr, h1v,
                                                      dinv, (float4*)agg2);
    k_gemm_pool<<<(NND + 63) / 64, 256, 0, stream>>>(agg2, W2, b2, ppool, t);
  }

  k_gru<<<1, 384, 0, stream>>>(ppool, wihT, whhT, b_ih, b_hh, fc_w, fc_b, out);
}

// Round 9
// 438.598 us; speedup vs baseline: 4.4116x; 1.4988x over previous
//
#include <hip/hip_runtime.h>
#include <hip/hip_fp8.h>
#include <hip/hip_bf16.h>

#define NND 50000
#define NE  1600000
#define TT  8
#define NBS ((NND + 255) / 256)   // 196 blocks over nodes
#define NBT2 ((NND + 63) / 64)    // 782 64-node tiles

// ---------------- fp8 / bf16 helpers ----------------

template <int I>
__device__ inline float fp8tof(unsigned int u) {
#if __has_builtin(__builtin_amdgcn_cvt_f32_fp8)
  return __builtin_amdgcn_cvt_f32_fp8(u, I);   // byte-select must be literal
#else
  __hip_fp8_e4m3 v; v.__x = (unsigned char)(u >> (I * 8)); return (float)v;
#endif
}

__device__ inline unsigned int pk4_fp8(float a, float b, float c, float d) {
#if __has_builtin(__builtin_amdgcn_cvt_pk_fp8_f32)
  int v = 0;
  v = __builtin_amdgcn_cvt_pk_fp8_f32(a, b, v, false);  // bytes 0,1
  v = __builtin_amdgcn_cvt_pk_fp8_f32(c, d, v, true);   // bytes 2,3
  return (unsigned int)v;
#else
  __hip_fp8_e4m3 qa(a), qb(b), qc(c), qd(d);
  return (unsigned int)qa.__x | ((unsigned int)qb.__x << 8) |
         ((unsigned int)qc.__x << 16) | ((unsigned int)qd.__x << 24);
#endif
}

__device__ inline unsigned int pkbf(float a, float b) {
  __hip_bfloat16 ha = __float2bfloat16(a), hb = __float2bfloat16(b);
  unsigned short ua = *(unsigned short*)&ha, ub = *(unsigned short*)&hb;
  return (unsigned int)ua | ((unsigned int)ub << 16);
}
__device__ inline float bl(unsigned int w) { return __uint_as_float(w << 16); }
__device__ inline float bh(unsigned int w) { return __uint_as_float(w & 0xffff0000u); }

// ---------------- preprocessing ----------------

__global__ void k_init(int* __restrict__ deg, float* __restrict__ ppool) {
  int i = blockIdx.x * 256 + threadIdx.x;
  if (i < NND) deg[i] = 1;              // self-loop
  if (i < TT * 64) ppool[i] = 0.f;
}

// degree histogram; atomic old-value = unique slot rank (>=1; slot 0 = self-loop)
__global__ void k_deg(const int* __restrict__ ei, int* __restrict__ deg,
                      int* __restrict__ rank) {
  int e = blockIdx.x * 256 + threadIdx.x;
  if (e < NE) rank[e] = atomicAdd(&deg[ei[NE + e]], 1);
}

__global__ void k_dinv(const int* __restrict__ deg, float* __restrict__ dinv) {
  int n = blockIdx.x * 256 + threadIdx.x;
  if (n < NND) dinv[n] = rsqrtf((float)deg[n]);
}

__global__ void k_scan1(const int* __restrict__ deg, int* __restrict__ bsum) {
  __shared__ int sh[256];
  int n = blockIdx.x * 256 + threadIdx.x;
  sh[threadIdx.x] = (n < NND) ? deg[n] : 0;
  __syncthreads();
  for (int o = 128; o > 0; o >>= 1) {
    if (threadIdx.x < o) sh[threadIdx.x] += sh[threadIdx.x + o];
    __syncthreads();
  }
  if (threadIdx.x == 0) bsum[blockIdx.x] = sh[0];
}

__global__ void k_scan2(const int* __restrict__ bsum, int* __restrict__ boff) {
  __shared__ int sh[256];
  int tid = threadIdx.x;
  int v = (tid < NBS) ? bsum[tid] : 0;
  sh[tid] = v;
  __syncthreads();
  for (int o = 1; o < 256; o <<= 1) {
    int t = (tid >= o) ? sh[tid - o] : 0;
    __syncthreads();
    sh[tid] += t;
    __syncthreads();
  }
  boff[tid] = sh[tid] - v;  // exclusive
}

__global__ void k_scan3(const int* __restrict__ deg, const int* __restrict__ boff,
                        int* __restrict__ offs, int* __restrict__ csr) {
  __shared__ int sh[256];
  int tid = threadIdx.x;
  int n = blockIdx.x * 256 + tid;
  int v = (n < NND) ? deg[n] : 0;
  sh[tid] = v;
  __syncthreads();
  for (int o = 1; o < 256; o <<= 1) {
    int t2 = (tid >= o) ? sh[tid - o] : 0;
    __syncthreads();
    sh[tid] += t2;
    __syncthreads();
  }
  if (n < NND) {
    int x = boff[blockIdx.x] + sh[tid] - v;  // exclusive global offset
    offs[n] = x;
    csr[x] = n;   // slot 0 = self-loop
  }
}

// atomic-free scatter; 2 dst-range passes keep the csr write window L2-resident
__global__ void k_scatter(const int* __restrict__ ei, const int* __restrict__ offs,
                          const int* __restrict__ rank, int* __restrict__ csr,
                          int lo, int hi) {
  int e = blockIdx.x * 256 + threadIdx.x;
  if (e < NE) {
    int d = ei[NE + e];
    if (d >= lo && d < hi) csr[offs[d] + rank[e]] = ei[e];
  }
}

// x_seq [T][N][3] f32 -> xs2 [N][T] uint2 (4 bf16: x0,x1,x2,pad, pre-scaled by dinv)
__global__ void k_xsb(const float* __restrict__ x, const float* __restrict__ dinv,
                      uint2* __restrict__ xs2) {
  int g = blockIdx.x * 256 + threadIdx.x;
  if (g >= NND * TT) return;
  int n = g >> 3, t = g & 7;
  const float* xx = x + ((size_t)t * NND + n) * 3;
  float dn = dinv[n];
  xs2[(size_t)n * 8 + t] = make_uint2(pkbf(xx[0] * dn, xx[1] * dn),
                                      pkbf(xx[2] * dn, 0.f));
}

// ---------------- fused layer 1: aggregate + W1 + ReLU + fp8 pack ----------------

// thread (n, tp): tp = t-pair (t=2tp, 2tp+1). uint4 gather = both timesteps per
// 16B load (half the loads of the per-(n,t) version). 200K threads.
__global__ void k_yh1(const int* __restrict__ offs, const int* __restrict__ deg,
                      const int* __restrict__ csr, const uint4* __restrict__ xs4,
                      const float* __restrict__ dinv, const float* __restrict__ W1,
                      const float* __restrict__ b1, uint4* __restrict__ h1w) {
  int g = blockIdx.x * 256 + threadIdx.x;
  int n = g >> 2, tp = g & 3;
  if (n >= NND) return;
  int o0 = offs[n], d = deg[n];
  float a0 = 0.f, a1 = 0.f, a2 = 0.f;   // t = 2tp
  float c0 = 0.f, c1 = 0.f, c2 = 0.f;   // t = 2tp+1
  int i = 0;
  for (; i + 4 <= d; i += 4) {
    int s0 = csr[o0 + i], s1 = csr[o0 + i + 1];
    int s2 = csr[o0 + i + 2], s3 = csr[o0 + i + 3];
    uint4 u0 = xs4[(size_t)s0 * 4 + tp];
    uint4 u1 = xs4[(size_t)s1 * 4 + tp];
    uint4 u2 = xs4[(size_t)s2 * 4 + tp];
    uint4 u3 = xs4[(size_t)s3 * 4 + tp];
    a0 += bl(u0.x) + bl(u1.x) + bl(u2.x) + bl(u3.x);
    a1 += bh(u0.x) + bh(u1.x) + bh(u2.x) + bh(u3.x);
    a2 += bl(u0.y) + bl(u1.y) + bl(u2.y) + bl(u3.y);
    c0 += bl(u0.z) + bl(u1.z) + bl(u2.z) + bl(u3.z);
    c1 += bh(u0.z) + bh(u1.z) + bh(u2.z) + bh(u3.z);
    c2 += bl(u0.w) + bl(u1.w) + bl(u2.w) + bl(u3.w);
  }
  for (; i < d; ++i) {
    uint4 u = xs4[(size_t)csr[o0 + i] * 4 + tp];
    a0 += bl(u.x); a1 += bh(u.x); a2 += bl(u.y);
    c0 += bl(u.z); c1 += bh(u.z); c2 += bl(u.w);
  }
  float dn = dinv[n];
#pragma unroll
  for (int j = 0; j < 2; ++j) {
    float y0 = (j ? c0 : a0) * dn, y1 = (j ? c1 : a1) * dn, y2 = (j ? c2 : a2) * dn;
    size_t base = ((size_t)(2 * tp + j) * NND + n) * 4;
#pragma unroll
    for (int k = 0; k < 4; ++k) {
      float vv[16];
#pragma unroll
      for (int m = 0; m < 16; ++m) {
        int c = k * 16 + m;
        float hv = fmaf(y2, W1[128 + c], fmaf(y1, W1[64 + c], fmaf(y0, W1[c], b1[c])));
        vv[m] = fmaxf(hv, 0.f) * dn;
      }
      uint4 o;
      o.x = pk4_fp8(vv[0], vv[1], vv[2], vv[3]);
      o.y = pk4_fp8(vv[4], vv[5], vv[6], vv[7]);
      o.z = pk4_fp8(vv[8], vv[9], vv[10], vv[11]);
      o.w = pk4_fp8(vv[12], vv[13], vv[14], vv[15]);
      h1w[base + k] = o;
    }
  }
}

// ---------------- fused layer 2: gather + W2 GEMM + relu + pool ----------------

#define ACC16(u) do { \
  acc[0]  += fp8tof<0>((u).x); acc[1]  += fp8tof<1>((u).x); acc[2]  += fp8tof<2>((u).x); acc[3]  += fp8tof<3>((u).x); \
  acc[4]  += fp8tof<0>((u).y); acc[5]  += fp8tof<1>((u).y); acc[6]  += fp8tof<2>((u).y); acc[7]  += fp8tof<3>((u).y); \
  acc[8]  += fp8tof<0>((u).z); acc[9]  += fp8tof<1>((u).z); acc[10] += fp8tof<2>((u).z); acc[11] += fp8tof<3>((u).z); \
  acc[12] += fp8tof<0>((u).w); acc[13] += fp8tof<1>((u).w); acc[14] += fp8tof<2>((u).w); acc[15] += fp8tof<3>((u).w); \
} while (0)

// One dispatch for ALL t: block b -> (t = b/NBT2, 64-node tile = b%NBT2).
// Phase 1 = round-8 k_agg2 decomposition (thread per (node,q), 4 lanes/node,
// uint4 loads, unroll-4 -> full TLP; round-4's fusion failure was SERIAL
// 32-node gathers per wave, not fusion per se). acc -> swizzled LDS As.
// Phase 2 = gemm_pool matmul + relu + pool. agg2 round-trip (205MB) gone.
__launch_bounds__(256)
__global__ void k_l2f(const int* __restrict__ offs, const int* __restrict__ deg,
                      const int* __restrict__ csr, const uint4* __restrict__ h1all,
                      const float* __restrict__ dinv, const float* __restrict__ W2,
                      const float* __restrict__ b2, float* __restrict__ ppool) {
  __shared__ float As[64 * 64];    // 16 KB, chunk-swizzled
  __shared__ float Ws[64 * 64];    // 16 KB, W2^T, chunk-swizzled
  __shared__ float pool[64];
  int tid = threadIdx.x;
  int t = blockIdx.x / NBT2;
  int rows0 = (blockIdx.x % NBT2) * 64;
  const uint4* h1v = h1all + (size_t)t * NND * 4;
  if (tid < 64) pool[tid] = 0.f;
  // Ws[j][swz(k)] = W2[k][j]
  for (int i = 0; i < 16; ++i) {
    int idx = i * 256 + tid;
    int k = idx >> 6, j = idx & 63;
    Ws[j * 64 + (((k >> 2) ^ ((j >> 3) & 7)) << 2) + (k & 3)] = W2[idx];
  }

  // ---- phase 1: gather (node row = tid>>2, q = tid&3 -> k = q*16+m) ----
  int row = tid >> 2, q = tid & 3;
  int n = rows0 + row;
  float acc[16];
#pragma unroll
  for (int m = 0; m < 16; ++m) acc[m] = 0.f;
  if (n < NND) {
    int o0 = offs[n], d = deg[n];
    int i = 0;
    for (; i + 4 <= d; i += 4) {
      int s0 = csr[o0 + i], s1 = csr[o0 + i + 1];
      int s2 = csr[o0 + i + 2], s3 = csr[o0 + i + 3];
      uint4 u0 = h1v[(size_t)s0 * 4 + q];
      uint4 u1 = h1v[(size_t)s1 * 4 + q];
      uint4 u2 = h1v[(size_t)s2 * 4 + q];
      uint4 u3 = h1v[(size_t)s3 * 4 + q];
      ACC16(u0); ACC16(u1); ACC16(u2); ACC16(u3);
    }
    for (; i < d; ++i) {
      uint4 u = h1v[(size_t)csr[o0 + i] * 4 + q];
      ACC16(u);
    }
  }
  float dn = (n < NND) ? dinv[n] : 0.f;
  int rsw = (row >> 3) & 7;
#pragma unroll
  for (int m = 0; m < 16; ++m) {
    int k = q * 16 + m;
    As[row * 64 + (((k >> 2) ^ rsw) << 2) + (k & 3)] = acc[m] * dn;
  }
  __syncthreads();

  // ---- phase 2: As[64,64] @ W2 -> relu+bias -> pool ----
  int rowg = tid >> 3, colg = tid & 7;
  int r0 = rowg * 2, c0 = colg * 8;
  float gac[2][8];
  for (int a = 0; a < 2; ++a)
    for (int b = 0; b < 8; ++b) gac[a][b] = 0.f;
  for (int k4 = 0; k4 < 16; ++k4) {
    float4 w[8];
    for (int cc = 0; cc < 8; ++cc)
      w[cc] = *(const float4*)&Ws[(c0 + cc) * 64 + ((k4 ^ colg) << 2)];
    for (int rr = 0; rr < 2; ++rr) {
      int r = r0 + rr;
      float4 av = *(const float4*)&As[r * 64 + ((k4 ^ ((r >> 3) & 7)) << 2)];
      for (int cc = 0; cc < 8; ++cc) {
        gac[rr][cc] += av.x * w[cc].x;
        gac[rr][cc] += av.y * w[cc].y;
        gac[rr][cc] += av.z * w[cc].z;
        gac[rr][cc] += av.w * w[cc].w;
      }
    }
  }

  float b2c[8];
  for (int cc = 0; cc < 8; ++cc) b2c[cc] = b2[c0 + cc];
  float csum[8];
  for (int cc = 0; cc < 8; ++cc) csum[cc] = 0.f;
  for (int rr = 0; rr < 2; ++rr) {
    if (rows0 + r0 + rr < NND) {
      for (int cc = 0; cc < 8; ++cc)
        csum[cc] += fmaxf(gac[rr][cc] + b2c[cc], 0.f);
    }
  }
  for (int cc = 0; cc < 8; ++cc) atomicAdd(&pool[c0 + cc], csum[cc]);
  __syncthreads();
  if (tid < 64) atomicAdd(&ppool[t * 64 + tid], pool[tid]);
}

// ---------------- GRU + fc ----------------

__global__ void k_twih(const float* __restrict__ w, float* __restrict__ wt) {
  int g = blockIdx.x * 256 + threadIdx.x;
  if (g < 384 * 64) { int r = g >> 6, k = g & 63; wt[k * 384 + r] = w[g]; }
}
__global__ void k_twhh(const float* __restrict__ w, float* __restrict__ wt) {
  int g = blockIdx.x * 256 + threadIdx.x;
  if (g < 384 * 128) { int r = g >> 7, k = g & 127; wt[k * 384 + r] = w[g]; }
}

__launch_bounds__(384, 2)
__global__ void k_gru(const float* __restrict__ ppool, const float* __restrict__ wihT,
                      const float* __restrict__ whhT, const float* __restrict__ b_ih,
                      const float* __restrict__ b_hh, const float* __restrict__ fc_w,
                      const float* __restrict__ fc_b, float* __restrict__ out) {
  __shared__ float x[64], h[128], gi_s[384], gh_s[384], red[128];
  int j = threadIdx.x;  // 0..383
  float wih[64];
#pragma unroll
  for (int k = 0; k < 64; ++k) wih[k] = wihT[k * 384 + j];
  float whh[128];
#pragma unroll
  for (int k = 0; k < 128; ++k) whh[k] = whhT[k * 384 + j];
  float bi = b_ih[j], bh2 = b_hh[j];
  if (j < 128) h[j] = 0.f;
  const float invn = 1.0f / (float)NND;
  for (int t = 0; t < TT; ++t) {
    if (j < 64) x[j] = ppool[t * 64 + j] * invn;
    __syncthreads();
    float gi = bi, gh = bh2;
#pragma unroll
    for (int k4 = 0; k4 < 16; ++k4) {
      float4 xv = *(const float4*)&x[k4 * 4];
      gi = fmaf(wih[k4 * 4 + 0], xv.x, gi);
      gi = fmaf(wih[k4 * 4 + 1], xv.y, gi);
      gi = fmaf(wih[k4 * 4 + 2], xv.z, gi);
      gi = fmaf(wih[k4 * 4 + 3], xv.w, gi);
    }
#pragma unroll
    for (int k4 = 0; k4 < 32; ++k4) {
      float4 hv = *(const float4*)&h[k4 * 4];
      gh = fmaf(whh[k4 * 4 + 0], hv.x, gh);
      gh = fmaf(whh[k4 * 4 + 1], hv.y, gh);
      gh = fmaf(whh[k4 * 4 + 2], hv.z, gh);
      gh = fmaf(whh[k4 * 4 + 3], hv.w, gh);
    }
    gi_s[j] = gi;
    gh_s[j] = gh;
    __syncthreads();
    if (j < 128) {
      float r = 1.f / (1.f + expf(-(gi_s[j] + gh_s[j])));
      float z = 1.f / (1.f + expf(-(gi_s[128 + j] + gh_s[128 + j])));
      float nn = tanhf(gi_s[256 + j] + r * gh_s[256 + j]);
      h[j] = (1.f - z) * nn + z * h[j];
    }
    __syncthreads();
  }
  if (j < 128) red[j] = h[j] * fc_w[j];
  __syncthreads();
  for (int o = 64; o > 0; o >>= 1) {
    if (j < o) red[j] += red[j + o];
    __syncthreads();
  }
  if (j == 0) out[0] = red[0] + fc_b[0];
}

// ---------------- launch ----------------

extern "C" void kernel_launch(void* const* d_in, const int* in_sizes, int n_in,
                              void* d_out, int out_size, void* d_ws, size_t ws_size,
                              hipStream_t stream) {
  const float* x_seq = (const float*)d_in[0];
  const int*   ei    = (const int*)d_in[1];
  const float* W1    = (const float*)d_in[2];
  const float* b1    = (const float*)d_in[3];
  const float* W2    = (const float*)d_in[4];
  const float* b2    = (const float*)d_in[5];
  const float* w_ih  = (const float*)d_in[6];
  const float* w_hh  = (const float*)d_in[7];
  const float* b_ih  = (const float*)d_in[8];
  const float* b_hh  = (const float*)d_in[9];
  const float* fc_w  = (const float*)d_in[10];
  const float* fc_b  = (const float*)d_in[11];
  float* out = (float*)d_out;

  char* p = (char*)d_ws;
  size_t off = 0;
  auto carve = [&](size_t bytes) -> char* {
    char* q = p + off;
    off += (bytes + 255) & ~(size_t)255;
    return q;
  };
  int*   deg    = (int*)carve((size_t)NND * 4);
  float* dinv   = (float*)carve((size_t)NND * 4);
  int*   offs   = (int*)carve((size_t)NND * 4);
  int*   bsum   = (int*)carve(256 * 4);
  int*   boff   = (int*)carve(256 * 4);
  int*   csr    = (int*)carve((size_t)(NE + NND) * 4);
  uint2* xs2    = (uint2*)carve((size_t)NND * 8 * 8);        // 3.2 MB
  float* ppool  = (float*)carve((size_t)TT * 64 * 4);
  float* wihT   = (float*)carve((size_t)384 * 64 * 4);
  float* whhT   = (float*)carve((size_t)384 * 128 * 4);
  char*  tail   = carve((size_t)TT * NND * 64);              // 25.6 MB: h1all
  uint4* h1all  = (uint4*)tail;
  int*   rank   = (int*)tail;   // alias: rank dead before h1all's first write

  k_init<<<NBS, 256, 0, stream>>>(deg, ppool);
  k_deg<<<(NE + 255) / 256, 256, 0, stream>>>(ei, deg, rank);
  k_dinv<<<NBS, 256, 0, stream>>>(deg, dinv);
  k_scan1<<<NBS, 256, 0, stream>>>(deg, bsum);
  k_scan2<<<1, 256, 0, stream>>>(bsum, boff);
  k_scan3<<<NBS, 256, 0, stream>>>(deg, boff, offs, csr);
  // 2 atomic-free dst-range passes (csr window ~3.3MB, L2-resident)
  for (int pp = 0; pp < 2; ++pp) {
    int lo = pp * (NND / 2), hi = (pp == 1) ? NND : (NND / 2);
    k_scatter<<<(NE + 255) / 256, 256, 0, stream>>>(ei, offs, rank, csr, lo, hi);
  }
  k_xsb<<<(NND * TT + 255) / 256, 256, 0, stream>>>(x_seq, dinv, xs2);
  k_twih<<<(384 * 64 + 255) / 256, 256, 0, stream>>>(w_ih, wihT);
  k_twhh<<<(384 * 128 + 255) / 256, 256, 0, stream>>>(w_hh, whhT);
  // fused layer-1, all t (rank dead from here; h1all reuses its space)
  k_yh1<<<(NND * 4 + 255) / 256, 256, 0, stream>>>(offs, deg, csr,
                                                   (const uint4*)xs2, dinv,
                                                   W1, b1, h1all);
  // fused layer-2 + pool, ALL t in one dispatch
  k_l2f<<<TT * NBT2, 256, 0, stream>>>(offs, deg, csr, h1all, dinv, W2, b2, ppool);

  k_gru<<<1, 384, 0, stream>>>(ppool, wihT, whhT, b_ih, b_hh, fc_w, fc_b, out);
}

// Round 11
// 394.403 us; speedup vs baseline: 4.9059x; 1.1121x over previous
//
#include <hip/hip_runtime.h>
#include <hip/hip_fp8.h>
#include <hip/hip_bf16.h>

#define NND 50000
#define NE  1600000
#define TT  8
#define NBS ((NND + 255) / 256)   // 196 blocks over nodes
#define NBT2 ((NND + 63) / 64)    // 782 64-node tiles

typedef __attribute__((ext_vector_type(2))) float f32x2;

// ---------------- fp8 / bf16 helpers ----------------

template <int I>
__device__ inline float fp8tof(unsigned int u) {
#if __has_builtin(__builtin_amdgcn_cvt_f32_fp8)
  return __builtin_amdgcn_cvt_f32_fp8(u, I);   // byte-select must be literal
#else
  __hip_fp8_e4m3 v; v.__x = (unsigned char)(u >> (I * 8)); return (float)v;
#endif
}

// packed: 2 fp8 -> 2 f32 in one instruction (word W: bytes 2W,2W+1 -> x,y)
template <bool W>
__device__ inline f32x2 cvtpk2(unsigned int u) {
#if __has_builtin(__builtin_amdgcn_cvt_pk_f32_fp8)
  return __builtin_amdgcn_cvt_pk_f32_fp8(u, W);
#else
  f32x2 r;
  r.x = fp8tof<W ? 2 : 0>(u);
  r.y = fp8tof<W ? 3 : 1>(u);
  return r;
#endif
}

__device__ inline unsigned int pk4_fp8(float a, float b, float c, float d) {
#if __has_builtin(__builtin_amdgcn_cvt_pk_fp8_f32)
  int v = 0;
  v = __builtin_amdgcn_cvt_pk_fp8_f32(a, b, v, false);  // bytes 0,1
  v = __builtin_amdgcn_cvt_pk_fp8_f32(c, d, v, true);   // bytes 2,3
  return (unsigned int)v;
#else
  __hip_fp8_e4m3 qa(a), qb(b), qc(c), qd(d);
  return (unsigned int)qa.__x | ((unsigned int)qb.__x << 8) |
         ((unsigned int)qc.__x << 16) | ((unsigned int)qd.__x << 24);
#endif
}

__device__ inline unsigned int pkbf(float a, float b) {
  __hip_bfloat16 ha = __float2bfloat16(a), hb = __float2bfloat16(b);
  unsigned short ua = *(unsigned short*)&ha, ub = *(unsigned short*)&hb;
  return (unsigned int)ua | ((unsigned int)ub << 16);
}
__device__ inline float bl(unsigned int w) { return __uint_as_float(w << 16); }
__device__ inline float bh(unsigned int w) { return __uint_as_float(w & 0xffff0000u); }

// ---------------- preprocessing ----------------

__global__ void k_init(int* __restrict__ deg, float* __restrict__ ppool) {
  int i = blockIdx.x * 256 + threadIdx.x;
  if (i < NND) deg[i] = 1;              // self-loop
  if (i < TT * 64) ppool[i] = 0.f;
}

// degree histogram; atomic old-value = unique slot rank (>=1; slot 0 = self-loop)
__global__ void k_deg(const int* __restrict__ ei, int* __restrict__ deg,
                      int* __restrict__ rank) {
  int e = blockIdx.x * 256 + threadIdx.x;
  if (e < NE) rank[e] = atomicAdd(&deg[ei[NE + e]], 1);
}

__global__ void k_dinv(const int* __restrict__ deg, float* __restrict__ dinv) {
  int n = blockIdx.x * 256 + threadIdx.x;
  if (n < NND) dinv[n] = rsqrtf((float)deg[n]);
}

__global__ void k_scan1(const int* __restrict__ deg, int* __restrict__ bsum) {
  __shared__ int sh[256];
  int n = blockIdx.x * 256 + threadIdx.x;
  sh[threadIdx.x] = (n < NND) ? deg[n] : 0;
  __syncthreads();
  for (int o = 128; o > 0; o >>= 1) {
    if (threadIdx.x < o) sh[threadIdx.x] += sh[threadIdx.x + o];
    __syncthreads();
  }
  if (threadIdx.x == 0) bsum[blockIdx.x] = sh[0];
}

__global__ void k_scan2(const int* __restrict__ bsum, int* __restrict__ boff) {
  __shared__ int sh[256];
  int tid = threadIdx.x;
  int v = (tid < NBS) ? bsum[tid] : 0;
  sh[tid] = v;
  __syncthreads();
  for (int o = 1; o < 256; o <<= 1) {
    int t = (tid >= o) ? sh[tid - o] : 0;
    __syncthreads();
    sh[tid] += t;
    __syncthreads();
  }
  boff[tid] = sh[tid] - v;  // exclusive
}

__global__ void k_scan3(const int* __restrict__ deg, const int* __restrict__ boff,
                        int* __restrict__ offs, int* __restrict__ csr) {
  __shared__ int sh[256];
  int tid = threadIdx.x;
  int n = blockIdx.x * 256 + tid;
  int v = (n < NND) ? deg[n] : 0;
  sh[tid] = v;
  __syncthreads();
  for (int o = 1; o < 256; o <<= 1) {
    int t2 = (tid >= o) ? sh[tid - o] : 0;
    __syncthreads();
    sh[tid] += t2;
    __syncthreads();
  }
  if (n < NND) {
    int x = boff[blockIdx.x] + sh[tid] - v;  // exclusive global offset
    offs[n] = x;
    csr[x] = n;   // slot 0 = self-loop
  }
}

// atomic-free scatter; 2 dst-range passes keep the csr write window L2-resident
__global__ void k_scatter(const int* __restrict__ ei, const int* __restrict__ offs,
                          const int* __restrict__ rank, int* __restrict__ csr,
                          int lo, int hi) {
  int e = blockIdx.x * 256 + threadIdx.x;
  if (e < NE) {
    int d = ei[NE + e];
    if (d >= lo && d < hi) csr[offs[d] + rank[e]] = ei[e];
  }
}

// x_seq [T][N][3] f32 -> xs2 [N][T] uint2 (4 bf16: x0,x1,x2,pad, pre-scaled by dinv)
__global__ void k_xsb(const float* __restrict__ x, const float* __restrict__ dinv,
                      uint2* __restrict__ xs2) {
  int g = blockIdx.x * 256 + threadIdx.x;
  if (g >= NND * TT) return;
  int n = g >> 3, t = g & 7;
  const float* xx = x + ((size_t)t * NND + n) * 3;
  float dn = dinv[n];
  xs2[(size_t)n * 8 + t] = make_uint2(pkbf(xx[0] * dn, xx[1] * dn),
                                      pkbf(xx[2] * dn, 0.f));
}

// ---------------- fused layer 1: aggregate + W1 + ReLU + fp8 pack ----------------

// thread (n, tp): tp = t-pair. uint4 gather = both timesteps per 16B load.
__global__ void k_yh1(const int* __restrict__ offs, const int* __restrict__ deg,
                      const int* __restrict__ csr, const uint4* __restrict__ xs4,
                      const float* __restrict__ dinv, const float* __restrict__ W1,
                      const float* __restrict__ b1, uint4* __restrict__ h1w) {
  int g = blockIdx.x * 256 + threadIdx.x;
  int n = g >> 2, tp = g & 3;
  if (n >= NND) return;
  int o0 = offs[n], d = deg[n];
  float a0 = 0.f, a1 = 0.f, a2 = 0.f;   // t = 2tp
  float c0 = 0.f, c1 = 0.f, c2 = 0.f;   // t = 2tp+1
  int i = 0;
  for (; i + 4 <= d; i += 4) {
    int s0 = csr[o0 + i], s1 = csr[o0 + i + 1];
    int s2 = csr[o0 + i + 2], s3 = csr[o0 + i + 3];
    uint4 u0 = xs4[(size_t)s0 * 4 + tp];
    uint4 u1 = xs4[(size_t)s1 * 4 + tp];
    uint4 u2 = xs4[(size_t)s2 * 4 + tp];
    uint4 u3 = xs4[(size_t)s3 * 4 + tp];
    a0 += bl(u0.x) + bl(u1.x) + bl(u2.x) + bl(u3.x);
    a1 += bh(u0.x) + bh(u1.x) + bh(u2.x) + bh(u3.x);
    a2 += bl(u0.y) + bl(u1.y) + bl(u2.y) + bl(u3.y);
    c0 += bl(u0.z) + bl(u1.z) + bl(u2.z) + bl(u3.z);
    c1 += bh(u0.z) + bh(u1.z) + bh(u2.z) + bh(u3.z);
    c2 += bl(u0.w) + bl(u1.w) + bl(u2.w) + bl(u3.w);
  }
  for (; i < d; ++i) {
    uint4 u = xs4[(size_t)csr[o0 + i] * 4 + tp];
    a0 += bl(u.x); a1 += bh(u.x); a2 += bl(u.y);
    c0 += bl(u.z); c1 += bh(u.z); c2 += bl(u.w);
  }
  float dn = dinv[n];
#pragma unroll
  for (int j = 0; j < 2; ++j) {
    float y0 = (j ? c0 : a0) * dn, y1 = (j ? c1 : a1) * dn, y2 = (j ? c2 : a2) * dn;
    size_t base = ((size_t)(2 * tp + j) * NND + n) * 4;
#pragma unroll
    for (int k = 0; k < 4; ++k) {
      float vv[16];
#pragma unroll
      for (int m = 0; m < 16; ++m) {
        int c = k * 16 + m;
        float hv = fmaf(y2, W1[128 + c], fmaf(y1, W1[64 + c], fmaf(y0, W1[c], b1[c])));
        vv[m] = fmaxf(hv, 0.f) * dn;
      }
      uint4 o;
      o.x = pk4_fp8(vv[0], vv[1], vv[2], vv[3]);
      o.y = pk4_fp8(vv[4], vv[5], vv[6], vv[7]);
      o.z = pk4_fp8(vv[8], vv[9], vv[10], vv[11]);
      o.w = pk4_fp8(vv[12], vv[13], vv[14], vv[15]);
      h1w[base + k] = o;
    }
  }
}

// ---------------- fused layer 2: gather + W2 GEMM + relu + pool ----------------

// packed converts + packed adds: 1 VALU instr/value (round-9: 2/value, VALU 51%)
#define ACCPK(u) do { \
  acc2[0] += cvtpk2<false>((u).x); acc2[1] += cvtpk2<true>((u).x); \
  acc2[2] += cvtpk2<false>((u).y); acc2[3] += cvtpk2<true>((u).y); \
  acc2[4] += cvtpk2<false>((u).z); acc2[5] += cvtpk2<true>((u).z); \
  acc2[6] += cvtpk2<false>((u).w); acc2[7] += cvtpk2<true>((u).w); \
} while (0)

// XCD-pinned: t = blockIdx.x & 7. Blocks round-robin to the 8 XCDs, so all
// blocks of timestep t land on XCD t -> its 3.2MB h1 slice is fetched into
// ONE L2 once (round-9 layout re-fetched every slice on every XCD: 266MB).
// As tile padded [64][68]: row stride 272B rotates bank index by 4 per row
// (the old 256B-stride + XOR swizzle was row-invariant in bank: 1.76e7 confl).
__launch_bounds__(256)
__global__ void k_l2f(const int* __restrict__ offs, const int* __restrict__ deg,
                      const int* __restrict__ csr, const uint4* __restrict__ h1all,
                      const float* __restrict__ dinv, const float* __restrict__ W2,
                      const float* __restrict__ b2, float* __restrict__ ppool) {
  __shared__ float As[64 * 68];    // 17 KB, padded (no swizzle)
  __shared__ float Ws[64 * 64];    // 16 KB, W2^T, chunk-swizzled
  __shared__ float pool[64];
  int tid = threadIdx.x;
  int t = blockIdx.x & 7;
  int rows0 = (blockIdx.x >> 3) * 64;
  const uint4* h1v = h1all + (size_t)t * NND * 4;
  if (tid < 64) pool[tid] = 0.f;
  // Ws[j][swz(k)] = W2[k][j]
  for (int i = 0; i < 16; ++i) {
    int idx = i * 256 + tid;
    int k = idx >> 6, j = idx & 63;
    Ws[j * 64 + (((k >> 2) ^ ((j >> 3) & 7)) << 2) + (k & 3)] = W2[idx];
  }

  // ---- phase 1: gather (node row = tid>>2, q = tid&3 -> k = q*16+m) ----
  int row = tid >> 2, q = tid & 3;
  int n = rows0 + row;
  f32x2 acc2[8];
#pragma unroll
  for (int m = 0; m < 8; ++m) acc2[m] = (f32x2)(0.f);
  if (n < NND) {
    int o0 = offs[n], d = deg[n];
    int i = 0;
    for (; i + 4 <= d; i += 4) {
      int s0 = csr[o0 + i], s1 = csr[o0 + i + 1];
      int s2 = csr[o0 + i + 2], s3 = csr[o0 + i + 3];
      uint4 u0 = h1v[(size_t)s0 * 4 + q];
      uint4 u1 = h1v[(size_t)s1 * 4 + q];
      uint4 u2 = h1v[(size_t)s2 * 4 + q];
      uint4 u3 = h1v[(size_t)s3 * 4 + q];
      ACCPK(u0); ACCPK(u1); ACCPK(u2); ACCPK(u3);
    }
    for (; i < d; ++i) {
      uint4 u = h1v[(size_t)csr[o0 + i] * 4 + q];
      ACCPK(u);
    }
  }
  float dn = (n < NND) ? dinv[n] : 0.f;
#pragma unroll
  for (int j = 0; j < 4; ++j) {
    *(float4*)&As[row * 68 + ((q * 4 + j) << 2)] =
        make_float4(acc2[2 * j].x * dn, acc2[2 * j].y * dn,
                    acc2[2 * j + 1].x * dn, acc2[2 * j + 1].y * dn);
  }
  __syncthreads();

  // ---- phase 2: As[64,64] @ W2 -> relu+bias -> pool ----
  int rowg = tid >> 3, colg = tid & 7;
  int r0 = rowg * 2, c0 = colg * 8;
  float gac[2][8];
  for (int a = 0; a < 2; ++a)
    for (int b = 0; b < 8; ++b) gac[a][b] = 0.f;
  for (int k4 = 0; k4 < 16; ++k4) {
    float4 w[8];
    for (int cc = 0; cc < 8; ++cc)
      w[cc] = *(const float4*)&Ws[(c0 + cc) * 64 + ((k4 ^ colg) << 2)];
    for (int rr = 0; rr < 2; ++rr) {
      int r = r0 + rr;
      float4 av = *(const float4*)&As[r * 68 + (k4 << 2)];
      for (int cc = 0; cc < 8; ++cc) {
        gac[rr][cc] += av.x * w[cc].x;
        gac[rr][cc] += av.y * w[cc].y;
        gac[rr][cc] += av.z * w[cc].z;
        gac[rr][cc] += av.w * w[cc].w;
      }
    }
  }

  float b2c[8];
  for (int cc = 0; cc < 8; ++cc) b2c[cc] = b2[c0 + cc];
  float csum[8];
  for (int cc = 0; cc < 8; ++cc) csum[cc] = 0.f;
  for (int rr = 0; rr < 2; ++rr) {
    if (rows0 + r0 + rr < NND) {
      for (int cc = 0; cc < 8; ++cc)
        csum[cc] += fmaxf(gac[rr][cc] + b2c[cc], 0.f);
    }
  }
  for (int cc = 0; cc < 8; ++cc) atomicAdd(&pool[c0 + cc], csum[cc]);
  __syncthreads();
  if (tid < 64) atomicAdd(&ppool[t * 64 + tid], pool[tid]);
}

// ---------------- GRU + fc ----------------

__global__ void k_twih(const float* __restrict__ w, float* __restrict__ wt) {
  int g = blockIdx.x * 256 + threadIdx.x;
  if (g < 384 * 64) { int r = g >> 6, k = g & 63; wt[k * 384 + r] = w[g]; }
}
__global__ void k_twhh(const float* __restrict__ w, float* __restrict__ wt) {
  int g = blockIdx.x * 256 + threadIdx.x;
  if (g < 384 * 128) { int r = g >> 7, k = g & 127; wt[k * 384 + r] = w[g]; }
}

__launch_bounds__(384, 2)
__global__ void k_gru(const float* __restrict__ ppool, const float* __restrict__ wihT,
                      const float* __restrict__ whhT, const float* __restrict__ b_ih,
                      const float* __restrict__ b_hh, const float* __restrict__ fc_w,
                      const float* __restrict__ fc_b, float* __restrict__ out) {
  __shared__ float x[64], h[128], gi_s[384], gh_s[384], red[128];
  int j = threadIdx.x;  // 0..383
  float wih[64];
#pragma unroll
  for (int k = 0; k < 64; ++k) wih[k] = wihT[k * 384 + j];
  float whh[128];
#pragma unroll
  for (int k = 0; k < 128; ++k) whh[k] = whhT[k * 384 + j];
  float bi = b_ih[j], bh2 = b_hh[j];
  if (j < 128) h[j] = 0.f;
  const float invn = 1.0f / (float)NND;
  for (int t = 0; t < TT; ++t) {
    if (j < 64) x[j] = ppool[t * 64 + j] * invn;
    __syncthreads();
    float gi = bi, gh = bh2;
#pragma unroll
    for (int k4 = 0; k4 < 16; ++k4) {
      float4 xv = *(const float4*)&x[k4 * 4];
      gi = fmaf(wih[k4 * 4 + 0], xv.x, gi);
      gi = fmaf(wih[k4 * 4 + 1], xv.y, gi);
      gi = fmaf(wih[k4 * 4 + 2], xv.z, gi);
      gi = fmaf(wih[k4 * 4 + 3], xv.w, gi);
    }
#pragma unroll
    for (int k4 = 0; k4 < 32; ++k4) {
      float4 hv = *(const float4*)&h[k4 * 4];
      gh = fmaf(whh[k4 * 4 + 0], hv.x, gh);
      gh = fmaf(whh[k4 * 4 + 1], hv.y, gh);
      gh = fmaf(whh[k4 * 4 + 2], hv.z, gh);
      gh = fmaf(whh[k4 * 4 + 3], hv.w, gh);
    }
    gi_s[j] = gi;
    gh_s[j] = gh;
    __syncthreads();
    if (j < 128) {
      float r = 1.f / (1.f + expf(-(gi_s[j] + gh_s[j])));
      float z = 1.f / (1.f + expf(-(gi_s[128 + j] + gh_s[128 + j])));
      float nn = tanhf(gi_s[256 + j] + r * gh_s[256 + j]);
      h[j] = (1.f - z) * nn + z * h[j];
    }
    __syncthreads();
  }
  if (j < 128) red[j] = h[j] * fc_w[j];
  __syncthreads();
  for (int o = 64; o > 0; o >>= 1) {
    if (j < o) red[j] += red[j + o];
    __syncthreads();
  }
  if (j == 0) out[0] = red[0] + fc_b[0];
}

// ---------------- launch ----------------

extern "C" void kernel_launch(void* const* d_in, const int* in_sizes, int n_in,
                              void* d_out, int out_size, void* d_ws, size_t ws_size,
                              hipStream_t stream) {
  const float* x_seq = (const float*)d_in[0];
  const int*   ei    = (const int*)d_in[1];
  const float* W1    = (const float*)d_in[2];
  const float* b1    = (const float*)d_in[3];
  const float* W2    = (const float*)d_in[4];
  const float* b2    = (const float*)d_in[5];
  const float* w_ih  = (const float*)d_in[6];
  const float* w_hh  = (const float*)d_in[7];
  const float* b_ih  = (const float*)d_in[8];
  const float* b_hh  = (const float*)d_in[9];
  const float* fc_w  = (const float*)d_in[10];
  const float* fc_b  = (const float*)d_in[11];
  float* out = (float*)d_out;

  char* p = (char*)d_ws;
  size_t off = 0;
  auto carve = [&](size_t bytes) -> char* {
    char* q = p + off;
    off += (bytes + 255) & ~(size_t)255;
    return q;
  };
  int*   deg    = (int*)carve((size_t)NND * 4);
  float* dinv   = (float*)carve((size_t)NND * 4);
  int*   offs   = (int*)carve((size_t)NND * 4);
  int*   bsum   = (int*)carve(256 * 4);
  int*   boff   = (int*)carve(256 * 4);
  int*   csr    = (int*)carve((size_t)(NE + NND) * 4);
  uint2* xs2    = (uint2*)carve((size_t)NND * 8 * 8);        // 3.2 MB
  float* ppool  = (float*)carve((size_t)TT * 64 * 4);
  float* wihT   = (float*)carve((size_t)384 * 64 * 4);
  float* whhT   = (float*)carve((size_t)384 * 128 * 4);
  char*  tail   = carve((size_t)TT * NND * 64);              // 25.6 MB: h1all
  uint4* h1all  = (uint4*)tail;
  int*   rank   = (int*)tail;   // alias: rank dead before h1all's first write

  k_init<<<NBS, 256, 0, stream>>>(deg, ppool);
  k_deg<<<(NE + 255) / 256, 256, 0, stream>>>(ei, deg, rank);
  k_dinv<<<NBS, 256, 0, stream>>>(deg, dinv);
  k_scan1<<<NBS, 256, 0, stream>>>(deg, bsum);
  k_scan2<<<1, 256, 0, stream>>>(bsum, boff);
  k_scan3<<<NBS, 256, 0, stream>>>(deg, boff, offs, csr);
  // 2 atomic-free dst-range passes (csr window ~3.3MB, L2-resident)
  for (int pp = 0; pp < 2; ++pp) {
    int lo = pp * (NND / 2), hi = (pp == 1) ? NND : (NND / 2);
    k_scatter<<<(NE + 255) / 256, 256, 0, stream>>>(ei, offs, rank, csr, lo, hi);
  }
  k_xsb<<<(NND * TT + 255) / 256, 256, 0, stream>>>(x_seq, dinv, xs2);
  k_twih<<<(384 * 64 + 255) / 256, 256, 0, stream>>>(w_ih, wihT);
  k_twhh<<<(384 * 128 + 255) / 256, 256, 0, stream>>>(w_hh, whhT);
  // fused layer-1, all t (rank dead from here; h1all reuses its space)
  k_yh1<<<(NND * 4 + 255) / 256, 256, 0, stream>>>(offs, deg, csr,
                                                   (const uint4*)xs2, dinv,
                                                   W1, b1, h1all);
  // fused layer-2 + pool, ALL t, XCD-pinned t-slices
  k_l2f<<<TT * NBT2, 256, 0, stream>>>(offs, deg, csr, h1all, dinv, W2, b2, ppool);

  k_gru<<<1, 384, 0, stream>>>(ppool, wihT, whhT, b_ih, b_hh, fc_w, fc_b, out);
}